// Round 9
// baseline (3145.559 us; speedup 1.0000x reference)
//
#include <hip/hip_runtime.h>
#include <hip/hip_bf16.h>

#define LAYERS 12
#define NHEAD  12
#define DHEAD  64
#define HDIM   768
#define FFDIM  3072
#define SEQ    1024
#define BATCH  4
#define WINSZ  256
#define MTOK   (BATCH*SEQ)          // 4096
#define PLANE  ((size_t)MTOK*HDIM)  // q/k/v plane elems: B*NH*S*DH = 3,145,728

typedef unsigned short u16;
typedef unsigned int   u32;

using f32x4  = __attribute__((ext_vector_type(4))) float;
using bf16x8 = __attribute__((ext_vector_type(8))) short;

__device__ __forceinline__ float bflo(u32 u){ union{u32 i;float f;}x; x.i = u << 16; return x.f; }
__device__ __forceinline__ float bfhi(u32 u){ union{u32 i;float f;}x; x.i = u & 0xffff0000u; return x.f; }
__device__ __forceinline__ u16 f2bf(float f){
    union{float f;u32 u;}x; x.f = f;
    u32 r = x.u + 0x7fffu + ((x.u >> 16) & 1u);   // RTNE
    return (u16)(r >> 16);
}
__device__ __forceinline__ void gload16(const u16* g, u16* l) {
    __builtin_amdgcn_global_load_lds(
        (const __attribute__((address_space(1))) u32*)g,
        (__attribute__((address_space(3))) u32*)l, 16, 0, 0);
}

// ---------------- reductions ----------------
__device__ __forceinline__ float wave_sum(float v) {
#pragma unroll
    for (int o = 32; o > 0; o >>= 1) v += __shfl_down(v, o, 64);
    return v;
}
__device__ __forceinline__ float wave_max(float v) {
#pragma unroll
    for (int o = 32; o > 0; o >>= 1) v = fmaxf(v, __shfl_down(v, o, 64));
    return v;
}
__device__ __forceinline__ float blk_sum256(float v, float* sm) {
    v = wave_sum(v);
    int lane = threadIdx.x & 63, w = threadIdx.x >> 6;
    __syncthreads();
    if (lane == 0) sm[w] = v;
    __syncthreads();
    return sm[0] + sm[1] + sm[2] + sm[3];
}
__device__ __forceinline__ float blk_sum1024(float v, float* sm) {
    v = wave_sum(v);
    int lane = threadIdx.x & 63, w = threadIdx.x >> 6;
    __syncthreads();
    if (lane == 0) sm[w] = v;
    __syncthreads();
    float r = 0.f;
#pragma unroll
    for (int i = 0; i < 16; i++) r += sm[i];
    return r;
}
__device__ __forceinline__ float blk_max1024(float v, float* sm) {
    v = wave_max(v);
    int lane = threadIdx.x & 63, w = threadIdx.x >> 6;
    __syncthreads();
    if (lane == 0) sm[w] = v;
    __syncthreads();
    float r = -1e30f;
#pragma unroll
    for (int i = 0; i < 16; i++) r = fmaxf(r, sm[i]);
    return r;
}

// ---------------- embedding + LN (writes h fp32 and hb bf16) ----------------
// float4-vectorized: threads 0..191 each own 4 dims; lanes 192-255 idle on mem ops
__global__ __launch_bounds__(256) void k_embed_ln(
    const float* __restrict__ WE, const float* __restrict__ PE,
    const float* __restrict__ g, const float* __restrict__ bta,
    const int* __restrict__ ids, float* __restrict__ h, u16* __restrict__ hb)
{
    __shared__ float sm[4];
    int tok = blockIdx.x;
    int s = tok & (SEQ - 1);
    int id = ids[tok];
    int tt = threadIdx.x;
    float4 x = make_float4(0.f, 0.f, 0.f, 0.f);
    if (tt < HDIM / 4) {
        float4 a = ((const float4*)(WE + (size_t)id * HDIM))[tt];
        float4 b = ((const float4*)(PE + (size_t)s * HDIM))[tt];
        x = make_float4(a.x + b.x, a.y + b.y, a.z + b.z, a.w + b.w);
    }
    float s1 = blk_sum256(x.x + x.y + x.z + x.w, sm);
    float s2 = blk_sum256(x.x*x.x + x.y*x.y + x.z*x.z + x.w*x.w, sm);
    float mean = s1 * (1.f / HDIM);
    float var  = s2 * (1.f / HDIM) - mean * mean;
    float inv  = rsqrtf(var + 1e-5f);
    if (tt < HDIM / 4) {
        float4 gg = ((const float4*)g)[tt];
        float4 bb = ((const float4*)bta)[tt];
        float4 o;
        o.x = (x.x - mean) * inv * gg.x + bb.x;
        o.y = (x.y - mean) * inv * gg.y + bb.y;
        o.z = (x.z - mean) * inv * gg.z + bb.z;
        o.w = (x.w - mean) * inv * gg.w + bb.w;
        ((float4*)(h + (size_t)tok * HDIM))[tt] = o;
        uint2 pk;
        pk.x = (u32)f2bf(o.x) | ((u32)f2bf(o.y) << 16);
        pk.y = (u32)f2bf(o.z) | ((u32)f2bf(o.w) << 16);
        ((uint2*)(hb + (size_t)tok * HDIM))[tt] = pk;
    }
}

// ---------------- in-place LN (h fp32, hb bf16 out) ----------------
// residual add happens in the GEMM epilogue (MODE 3); this is pure LN
__global__ __launch_bounds__(256) void k_ln(
    float* __restrict__ h,
    const float* __restrict__ g, const float* __restrict__ bta, u16* __restrict__ hb)
{
    __shared__ float sm[4];
    int tok = blockIdx.x;
    int tt = threadIdx.x;
    float4 x = make_float4(0.f, 0.f, 0.f, 0.f);
    if (tt < HDIM / 4) {
        x = ((const float4*)(h + (size_t)tok * HDIM))[tt];
    }
    float s1 = blk_sum256(x.x + x.y + x.z + x.w, sm);
    float s2 = blk_sum256(x.x*x.x + x.y*x.y + x.z*x.z + x.w*x.w, sm);
    float mean = s1 * (1.f / HDIM);
    float var  = s2 * (1.f / HDIM) - mean * mean;
    float inv  = rsqrtf(var + 1e-5f);
    if (tt < HDIM / 4) {
        float4 gg = ((const float4*)g)[tt];
        float4 bb = ((const float4*)bta)[tt];
        float4 o;
        o.x = (x.x - mean) * inv * gg.x + bb.x;
        o.y = (x.y - mean) * inv * gg.y + bb.y;
        o.z = (x.z - mean) * inv * gg.z + bb.z;
        o.w = (x.w - mean) * inv * gg.w + bb.w;
        ((float4*)(h + (size_t)tok * HDIM))[tt] = o;
        uint2 pk;
        pk.x = (u32)f2bf(o.x) | ((u32)f2bf(o.y) << 16);
        pk.y = (u32)f2bf(o.z) | ((u32)f2bf(o.w) << 16);
        ((uint2*)(hb + (size_t)tok * HDIM))[tt] = pk;
    }
}

// ---------------- transpose + fp32->bf16: W[K][N] -> dst[N][K] ----------------
// grid (N/32, K/32, nlayers), 256 threads; ss/ds = per-layer element strides
__global__ __launch_bounds__(256) void k_cvtT(
    const float* __restrict__ W, u16* __restrict__ dst, int K, int N,
    size_t ss, size_t ds)
{
    __shared__ float t[32][33];
    W   += (size_t)blockIdx.z * ss;
    dst += (size_t)blockIdx.z * ds;
    int n0 = blockIdx.x * 32, k0 = blockIdx.y * 32;
    int c = threadIdx.x & 31, r8 = threadIdx.x >> 5;
#pragma unroll
    for (int p = 0; p < 4; p++) {
        int k = r8 + p * 8;
        t[k][c] = W[(size_t)(k0 + k) * N + n0 + c];
    }
    __syncthreads();
#pragma unroll
    for (int p = 0; p < 2; p++) {
        int idx = threadIdx.x + p * 256;       // 0..511 over 32 n-rows x 16 k-pairs
        int n = idx >> 4, kp = idx & 15;
        float a = t[kp*2][n], b = t[kp*2+1][n];
        u32 pk = (u32)f2bf(a) | ((u32)f2bf(b) << 16);
        u32* d = (u32*)(dst + (size_t)(n0 + n) * K + k0);
        d[kp] = pk;
    }
}

// ---------------- MFMA GEMM: C[M,N] = A[M,K](bf16) @ BT[N,K]^T(bf16) ----------------
// NS BK=32 K-subtiles staged per barrier pair (LDS [NS][BM][32]): amortizes the
// vmcnt-drain barrier cost; per-subtile addressing identical to the verified
// single-subtile kernel. K must be a multiple of 32*NS.
// MODE 0: C fp32 [M,N] (+bias b0)
// MODE 1: QKV split -> bf16 planes [3][B,NH,S,DH], biases b0/b1/b2
// MODE 2: GELU -> bf16 [M,N]
// MODE 3: residual: C fp32 [M,N] += val (+bias b0)
template<int BM, int BN, int MODE, int NS>
__global__ __launch_bounds__(256) void k_gemm_mfma(
    const u16* __restrict__ A, const u16* __restrict__ BT,
    const float* __restrict__ b0, const float* __restrict__ b1, const float* __restrict__ b2,
    void* __restrict__ C, int K, int N)
{
    __shared__ u16 As[NS * BM * 32];
    __shared__ u16 Bs[NS * BN * 32];
    const int tid = threadIdx.x, lane = tid & 63, w = tid >> 6;
    const int bm = blockIdx.y * BM, bn = blockIdx.x * BN;
    constexpr int MT = BM / 32, NT = BN / 32;      // mfma tiles per wave
    constexpr int AR = BM / 4, BR = BN / 4;        // staging rows per wave
    constexpr int AI = AR / 16, BI = BR / 16;      // lds-dma instrs per wave per subtile
    const int wm = (w & 1) * (BM / 2), wn = (w >> 1) * (BN / 2);

    f32x4 acc[MT][NT];
#pragma unroll
    for (int mi = 0; mi < MT; mi++)
#pragma unroll
        for (int ni = 0; ni < NT; ni++) acc[mi][ni] = (f32x4){0.f, 0.f, 0.f, 0.f};

    const u16* ag = A  + (size_t)(bm + w * AR + (lane >> 2)) * K + (lane & 3) * 8;
    const u16* bg = BT + (size_t)(bn + w * BR + (lane >> 2)) * K + (lane & 3) * 8;
    u16* al = As + w * AR * 32;
    u16* bl = Bs + w * BR * 32;
    const int fr = lane & 15, fq = (lane >> 4) * 8;

    for (int k0 = 0; k0 < K; k0 += 32 * NS) {
#pragma unroll
        for (int s = 0; s < NS; s++) {
#pragma unroll
            for (int i = 0; i < AI; i++)
                gload16(ag + (size_t)i * 16 * K + k0 + s * 32, al + s * BM * 32 + i * 512);
#pragma unroll
            for (int i = 0; i < BI; i++)
                gload16(bg + (size_t)i * 16 * K + k0 + s * 32, bl + s * BN * 32 + i * 512);
        }
        __syncthreads();
#pragma unroll
        for (int s = 0; s < NS; s++) {
            bf16x8 af[MT], bf[NT];
#pragma unroll
            for (int mi = 0; mi < MT; mi++)
                af[mi] = *(const bf16x8*)(As + s * BM * 32 + (wm + mi * 16 + fr) * 32 + fq);
#pragma unroll
            for (int ni = 0; ni < NT; ni++)
                bf[ni] = *(const bf16x8*)(Bs + s * BN * 32 + (wn + ni * 16 + fr) * 32 + fq);
#pragma unroll
            for (int mi = 0; mi < MT; mi++)
#pragma unroll
                for (int ni = 0; ni < NT; ni++)
                    acc[mi][ni] = __builtin_amdgcn_mfma_f32_16x16x32_bf16(af[mi], bf[ni], acc[mi][ni], 0, 0, 0);
        }
        __syncthreads();
    }

#pragma unroll
    for (int mi = 0; mi < MT; mi++) {
        int m_base = bm + wm + mi * 16 + (lane >> 4) * 4;
#pragma unroll
        for (int ni = 0; ni < NT; ni++) {
            int n_g = bn + wn + ni * 16 + (lane & 15);
            const float* bp = b0; int nn = n_g; int which = 0;
            if (MODE == 1) {
                if (n_g >= 1536)      { bp = b2; nn = n_g - 1536; which = 2; }
                else if (n_g >= 768)  { bp = b1; nn = n_g - 768;  which = 1; }
            }
            float bias = bp[nn];
#pragma unroll
            for (int r = 0; r < 4; r++) {
                int m_g = m_base + r;
                float val = acc[mi][ni][r] + bias;
                if (MODE == 0) {
                    ((float*)C)[(size_t)m_g * N + n_g] = val;
                } else if (MODE == 1) {
                    int bb = m_g >> 10, ss = m_g & 1023;
                    int hh = nn >> 6, dd = nn & 63;
                    ((u16*)C)[(size_t)which * PLANE + (((size_t)bb * NHEAD + hh) * SEQ + ss) * DHEAD + dd] = f2bf(val);
                } else if (MODE == 3) {
                    float* p = (float*)C + (size_t)m_g * N + n_g;
                    *p += val;
                } else {
                    val = 0.5f * val * (1.f + erff(val * 0.70710678118f));
                    ((u16*)C)[(size_t)m_g * N + n_g] = f2bf(val);
                }
            }
        }
    }
}

// ---------------- MFMA banded local attention ----------------
// One block per (b, h, 64-row q tile). 4 waves; wave w owns q rows [w*16, w*16+16).
// Keys iterated in 9 chunks of 64 covering span [q0-256, q0+319].
// QK^T and PV both via mfma_f32_16x16x32_bf16; online softmax held in registers
// (each lane owns 4 q rows; row-reduce = shfl_xor butterfly over the 16 key lanes).
// LDS rows padded to 72 u16 (144 B): keeps ds_read_b128 16B-aligned and breaks the
// 128B-stride same-bank pattern.
#define PADW 72
__global__ __launch_bounds__(256) void k_attn_mfma(
    const u16* __restrict__ qkv, const int* __restrict__ mask, u16* __restrict__ abuf)
{
    __shared__ u16 Qs[64 * PADW];
    __shared__ u16 Ks[64 * PADW];
    __shared__ u16 Vt[64 * PADW];   // transposed: [dh][key]
    __shared__ u16 Ps[64 * PADW];   // probs bf16: [q][key]
    __shared__ int ms[64];
    const int tid = threadIdx.x, lane = tid & 63, w = tid >> 6;
    int blk = blockIdx.x;
    int qt = blk & 15;
    int hh = (blk >> 4) % NHEAD;
    int b  = blk / (16 * NHEAD);
    int q0 = qt * 64;

    const u16* qp = qkv + ((size_t)b * NHEAD + hh) * SEQ * DHEAD;
    const u16* kp = qp + PLANE;
    const u16* vp = qp + 2 * PLANE;

    // stage Q tile [64][64] once
#pragma unroll
    for (int it = 0; it < 2; it++) {
        int idx = tid + it * 256;            // 512 segs = 64 rows x 8 col-segs
        int r = idx >> 3, c8 = (idx & 7) * 8;
        uint4 u = *(const uint4*)(qp + (size_t)(q0 + r) * DHEAD + c8);
        *(uint4*)(Qs + r * PADW + c8) = u;
    }

    const int fr = lane & 15, g4 = (lane >> 4) * 4, fq = (lane >> 4) * 8;
    const int wq = w * 16;
    const int qpos = q0 + wq + g4;           // +r gives this lane's q rows

    f32x4 o[4];                               // out acc: [dh tile][q row r]
#pragma unroll
    for (int d = 0; d < 4; d++) o[d] = (f32x4){0.f, 0.f, 0.f, 0.f};
    float mr[4], ll[4];
#pragma unroll
    for (int r = 0; r < 4; r++) { mr[r] = -1e9f; ll[r] = 0.f; }

    __syncthreads();
    bf16x8 aq[2];                             // Q A-frags, persist across chunks
#pragma unroll
    for (int ks = 0; ks < 2; ks++)
        aq[ks] = *(const bf16x8*)(Qs + (wq + fr) * PADW + ks * 32 + fq);

    for (int ch = 0; ch < 9; ch++) {
        int kbase = q0 - 256 + ch * 64;
        __syncthreads();                      // prev chunk's PV reads done
        // stage K rows [64][64]
#pragma unroll
        for (int it = 0; it < 2; it++) {
            int idx = tid + it * 256;
            int r = idx >> 3, c8 = (idx & 7) * 8;
            int kq = kbase + r;
            uint4 u = (kq >= 0 && kq < SEQ)
                ? *(const uint4*)(kp + (size_t)kq * DHEAD + c8)
                : make_uint4(0u, 0u, 0u, 0u);
            *(uint4*)(Ks + r * PADW + c8) = u;
        }
        // stage V transposed: thread handles key r = tid>>2, dh seg (tid&3)*16
        {
            int r = tid >> 2, sg = (tid & 3) * 16;
            int kq = kbase + r;
            uint4 u0 = make_uint4(0u,0u,0u,0u), u1 = u0;
            if (kq >= 0 && kq < SEQ) {
                const uint4* vr = (const uint4*)(vp + (size_t)kq * DHEAD + sg);
                u0 = vr[0]; u1 = vr[1];
            }
            u32 ww[8] = {u0.x, u0.y, u0.z, u0.w, u1.x, u1.y, u1.z, u1.w};
#pragma unroll
            for (int j = 0; j < 8; j++) {
                Vt[(sg + 2*j    ) * PADW + r] = (u16)(ww[j] & 0xffffu);
                Vt[(sg + 2*j + 1) * PADW + r] = (u16)(ww[j] >> 16);
            }
        }
        if (tid < 64) {
            int kq = kbase + tid;
            ms[tid] = (kq >= 0 && kq < SEQ) ? mask[b * SEQ + kq] : 0;
        }
        __syncthreads();

        // QK^T: s[nt][r] = score[q = wq+g4+r][key = nt*16+fr]
        f32x4 s[4];
#pragma unroll
        for (int nt = 0; nt < 4; nt++) s[nt] = (f32x4){0.f, 0.f, 0.f, 0.f};
#pragma unroll
        for (int nt = 0; nt < 4; nt++)
#pragma unroll
            for (int ks = 0; ks < 2; ks++) {
                bf16x8 bk = *(const bf16x8*)(Ks + (nt*16 + fr) * PADW + ks*32 + fq);
                s[nt] = __builtin_amdgcn_mfma_f32_16x16x32_bf16(aq[ks], bk, s[nt], 0, 0, 0);
            }

        // scale + band/mask, per-lane chunk max
        float mloc[4];
#pragma unroll
        for (int r = 0; r < 4; r++) mloc[r] = -1e9f;
#pragma unroll
        for (int nt = 0; nt < 4; nt++) {
            int kpos = kbase + nt*16 + fr;
            int msv = ms[nt*16 + fr];
#pragma unroll
            for (int r = 0; r < 4; r++) {
                int dq = kpos - (qpos + r);
                bool ok = (dq >= -WINSZ) && (dq <= WINSZ) && (msv != 0);
                float sv = ok ? s[nt][r] * 0.125f : -1e9f;
                s[nt][r] = sv;
                mloc[r] = fmaxf(mloc[r], sv);
            }
        }
        // butterfly max over the 16 key lanes
#pragma unroll
        for (int mk = 1; mk < 16; mk <<= 1)
#pragma unroll
            for (int r = 0; r < 4; r++)
                mloc[r] = fmaxf(mloc[r], __shfl_xor(mloc[r], mk, 64));

        float sc4[4], psum[4];
#pragma unroll
        for (int r = 0; r < 4; r++) {
            float mn = fmaxf(mr[r], mloc[r]);
            sc4[r] = __expf(mr[r] - mn);
            mr[r] = mn;
            psum[r] = 0.f;
        }
        // p = exp(s - m), write bf16 P to LDS (rows owned by this wave only)
#pragma unroll
        for (int nt = 0; nt < 4; nt++)
#pragma unroll
            for (int r = 0; r < 4; r++) {
                float p = (s[nt][r] > -1e8f) ? __expf(s[nt][r] - mr[r]) : 0.f;
                psum[r] += p;
                Ps[(wq + g4 + r) * PADW + nt*16 + fr] = f2bf(p);
            }
        // butterfly sum over key lanes
#pragma unroll
        for (int mk = 1; mk < 16; mk <<= 1)
#pragma unroll
            for (int r = 0; r < 4; r++)
                psum[r] += __shfl_xor(psum[r], mk, 64);

        f32x4 scv = (f32x4){sc4[0], sc4[1], sc4[2], sc4[3]};
#pragma unroll
        for (int r = 0; r < 4; r++) ll[r] = ll[r] * sc4[r] + psum[r];
#pragma unroll
        for (int d = 0; d < 4; d++) o[d] *= scv;

        // PV: o[d] += P[q,keys] @ Vt[dh,keys]^T  (same-wave LDS write->read, in-order)
#pragma unroll
        for (int ks = 0; ks < 2; ks++) {
            bf16x8 ap = *(const bf16x8*)(Ps + (wq + fr) * PADW + ks*32 + fq);
#pragma unroll
            for (int d = 0; d < 4; d++) {
                bf16x8 bv8 = *(const bf16x8*)(Vt + (d*16 + fr) * PADW + ks*32 + fq);
                o[d] = __builtin_amdgcn_mfma_f32_16x16x32_bf16(ap, bv8, o[d], 0, 0, 0);
            }
        }
    }

    // epilogue: normalize and store bf16 to abuf[B,S,H]
#pragma unroll
    for (int r = 0; r < 4; r++) {
        float inv = 1.f / ll[r];
        u16* orow = abuf + ((size_t)(b * SEQ + q0 + wq + g4 + r)) * HDIM + hh * DHEAD;
#pragma unroll
        for (int d = 0; d < 4; d++)
            orow[d*16 + fr] = f2bf(o[d][r] * inv);
    }
}

// ---------------- attention-pool head (parallelized) ----------------
// Phase A: sc[tok] = h[tok]·aw — one wave per token, grid MTOK/4 x 256
__global__ __launch_bounds__(256) void k_pool_score(
    const float* __restrict__ h, const float* __restrict__ aw, float* __restrict__ sc)
{
    int tok = blockIdx.x * 4 + (threadIdx.x >> 6);
    int lane = threadIdx.x & 63;
    const float4* hr = (const float4*)(h + (size_t)tok * HDIM);
    const float4* ar = (const float4*)aw;
    float acc = 0.f;
#pragma unroll
    for (int i = 0; i < 3; i++) {
        int c = lane + i * 64;               // 192 float4 per row
        float4 x = hr[c], a = ar[c];
        acc += x.x*a.x + x.y*a.y + x.z*a.z + x.w*a.w;
    }
    acc = wave_sum(acc);
    if (lane == 0) sc[tok] = acc;
}

// Phase B: softmax over s per batch — grid B x 1024; sc in-place -> probs
__global__ __launch_bounds__(1024) void k_pool_softmax(float* __restrict__ sc)
{
    __shared__ float red[16];
    int b = blockIdx.x;
    float v = sc[b * SEQ + threadIdx.x];
    float mx = blk_max1024(v, red);
    float e = __expf(v - mx);
    float tot = blk_sum1024(e, red);
    sc[b * SEQ + threadIdx.x] = e / tot;
}

// Phase C: partial weighted sums over 64-row s-slices — grid (B,16) x 256
// partial[b][j][d] = sum_{s in slice j} h[b][s][d] * ps[b][s]
__global__ __launch_bounds__(256) void k_pool_reduce(
    const float* __restrict__ h, const float* __restrict__ ps, float* __restrict__ partial)
{
    int b = blockIdx.x, j = blockIdx.y;
    int tid = threadIdx.x;
    const float* hb = h + ((size_t)b * SEQ + j * 64) * HDIM;
    const float* pp = ps + b * SEQ + j * 64;
    float a0 = 0.f, a1 = 0.f, a2 = 0.f;
    for (int s = 0; s < 64; s++) {
        float p = pp[s];
        const float* row = hb + (size_t)s * HDIM;
        a0 = fmaf(row[tid],       p, a0);
        a1 = fmaf(row[tid + 256], p, a1);
        a2 = fmaf(row[tid + 512], p, a2);
    }
    float* outp = partial + ((size_t)b * 16 + j) * HDIM;
    outp[tid] = a0; outp[tid + 256] = a1; outp[tid + 512] = a2;
}

// Phase D: reduce 16 partials, dot with Wc — grid B x 256
__global__ __launch_bounds__(256) void k_pool_final(
    const float* __restrict__ partial, const float* __restrict__ Wc,
    const float* __restrict__ bc, float* __restrict__ out)
{
    __shared__ float sm[4];
    int b = blockIdx.x, tid = threadIdx.x;
    float acc = 0.f;
#pragma unroll
    for (int dd = 0; dd < 3; dd++) {
        int d = tid + dd * 256;
        float pd = 0.f;
#pragma unroll
        for (int j = 0; j < 16; j++)
            pd += partial[((size_t)b * 16 + j) * HDIM + d];
        acc = fmaf(pd, Wc[d], acc);
    }
    float total = blk_sum256(acc, sm);
    if (tid == 0) out[b] = total + bc[0];
}

// ---------------- launcher ----------------
extern "C" void kernel_launch(void* const* d_in, const int* in_sizes, int n_in,
                              void* d_out, int out_size, void* d_ws, size_t ws_size,
                              hipStream_t stream)
{
    const float* WE    = (const float*)d_in[0];
    const float* PE    = (const float*)d_in[1];
    const float* Eg    = (const float*)d_in[2];
    const float* Eb    = (const float*)d_in[3];
    const float* Wq    = (const float*)d_in[4];
    const float* bq    = (const float*)d_in[5];
    const float* Wk    = (const float*)d_in[6];
    const float* bk    = (const float*)d_in[7];
    const float* Wv    = (const float*)d_in[8];
    const float* bv    = (const float*)d_in[9];
    const float* Wo    = (const float*)d_in[10];
    const float* bo    = (const float*)d_in[11];
    const float* g1    = (const float*)d_in[12];
    const float* beta1 = (const float*)d_in[13];
    const float* W1    = (const float*)d_in[14];
    const float* b1    = (const float*)d_in[15];
    const float* W2    = (const float*)d_in[16];
    const float* b2    = (const float*)d_in[17];
    const float* g2    = (const float*)d_in[18];
    const float* beta2 = (const float*)d_in[19];
    const float* aw    = (const float*)d_in[20];
    const float* Wc    = (const float*)d_in[21];
    const float* bc    = (const float*)d_in[22];
    const int* ids     = (const int*)d_in[23];
    const int* msk     = (const int*)d_in[24];

    char* base = (char*)d_ws;
    float* h    = (float*)base;                               base += (size_t)MTOK * HDIM * 4;   // 12.6MB
    float* tbuf = (float*)base;                               base += (size_t)MTOK * HDIM * 4;   // 12.6MB (pool scratch)
    u16*   hb   = (u16*)base;                                 base += (size_t)MTOK * HDIM * 2;   // 6.3MB
    u16*   X    = (u16*)base;                                 base += (size_t)MTOK * FFDIM * 2;  // 25.2MB
    u16*   qkv  = X;                                          // 3 planes of PLANE
    u16*   abuf = X + 3 * PLANE;                              // [B,S,H] bf16
    u16*   mid  = X;                                          // FF1 out aliases qkv/abuf (dead)

    // weight buffers: if workspace allows, convert ALL layers once up front
    const size_t sQKV = (size_t)2304 * HDIM;   // per-layer elems
    const size_t sWO  = (size_t)HDIM * HDIM;
    const size_t sW1  = (size_t)FFDIM * HDIM;
    const size_t sW2  = (size_t)HDIM * FFDIM;
    size_t fixed = (size_t)(base - (char*)d_ws);
    size_t all_bytes = fixed + (size_t)LAYERS * (sQKV + sWO + sW1 + sW2) * 2;
    bool wsall = ws_size >= all_bytes;
    int NL = wsall ? LAYERS : 1;
    u16* wqkvT = (u16*)base;
    u16* woT   = wqkvT + sQKV * NL;
    u16* w1T   = woT   + sWO  * NL;
    u16* w2T   = w1T   + sW1  * NL;

    k_embed_ln<<<MTOK, 256, 0, stream>>>(WE, PE, Eg, Eb, ids, h, hb);

    if (wsall) {
        k_cvtT<<<dim3(24, 24, LAYERS), 256, 0, stream>>>(Wq, wqkvT,                     HDIM, HDIM, (size_t)HDIM*HDIM, sQKV);
        k_cvtT<<<dim3(24, 24, LAYERS), 256, 0, stream>>>(Wk, wqkvT + (size_t)HDIM*HDIM, HDIM, HDIM, (size_t)HDIM*HDIM, sQKV);
        k_cvtT<<<dim3(24, 24, LAYERS), 256, 0, stream>>>(Wv, wqkvT + (size_t)2*HDIM*HDIM, HDIM, HDIM, (size_t)HDIM*HDIM, sQKV);
        k_cvtT<<<dim3(24, 24, LAYERS), 256, 0, stream>>>(Wo, woT, HDIM, HDIM, (size_t)HDIM*HDIM, sWO);
        k_cvtT<<<dim3(96, 24, LAYERS), 256, 0, stream>>>(W1, w1T, HDIM, FFDIM, (size_t)HDIM*FFDIM, sW1);
        k_cvtT<<<dim3(24, 96, LAYERS), 256, 0, stream>>>(W2, w2T, FFDIM, HDIM, (size_t)FFDIM*HDIM, sW2);
    }

    for (int l = 0; l < LAYERS; l++) {
        u16* wqkvT_l = wqkvT + (wsall ? (size_t)l * sQKV : 0);
        u16* woT_l   = woT   + (wsall ? (size_t)l * sWO  : 0);
        u16* w1T_l   = w1T   + (wsall ? (size_t)l * sW1  : 0);
        u16* w2T_l   = w2T   + (wsall ? (size_t)l * sW2  : 0);

        if (!wsall) {
            const float* Wql = Wq + (size_t)l * HDIM * HDIM;
            const float* Wkl = Wk + (size_t)l * HDIM * HDIM;
            const float* Wvl = Wv + (size_t)l * HDIM * HDIM;
            const float* Wol = Wo + (size_t)l * HDIM * HDIM;
            const float* W1l = W1 + (size_t)l * HDIM * FFDIM;
            const float* W2l = W2 + (size_t)l * FFDIM * HDIM;
            k_cvtT<<<dim3(24, 24), 256, 0, stream>>>(Wql, wqkvT_l,                      HDIM, HDIM, 0, 0);
            k_cvtT<<<dim3(24, 24), 256, 0, stream>>>(Wkl, wqkvT_l + (size_t)HDIM*HDIM,  HDIM, HDIM, 0, 0);
            k_cvtT<<<dim3(24, 24), 256, 0, stream>>>(Wvl, wqkvT_l + (size_t)2*HDIM*HDIM,HDIM, HDIM, 0, 0);
            k_cvtT<<<dim3(24, 24), 256, 0, stream>>>(Wol, woT_l, HDIM, HDIM, 0, 0);
            k_cvtT<<<dim3(96, 24), 256, 0, stream>>>(W1l, w1T_l, HDIM, FFDIM, 0, 0);
            k_cvtT<<<dim3(24, 96), 256, 0, stream>>>(W2l, w2T_l, FFDIM, HDIM, 0, 0);
        }

        // QKV fused: [4096,768] @ [768,2304]
        k_gemm_mfma<128, 128, 1, 3><<<dim3(2304/128, MTOK/128), 256, 0, stream>>>(
            hb, wqkvT_l, bq + l*HDIM, bk + l*HDIM, bv + l*HDIM, qkv, HDIM, 2304);
        // banded attention (MFMA)
        k_attn_mfma<<<BATCH * NHEAD * (SEQ/64), 256, 0, stream>>>(qkv, msk, abuf);
        // attn out proj: [4096,768] @ [768,768], residual-add into h
        k_gemm_mfma<128, 64, 3, 3><<<dim3(HDIM/64, MTOK/128), 256, 0, stream>>>(
            abuf, woT_l, bo + l*HDIM, nullptr, nullptr, h, HDIM, HDIM);
        k_ln<<<MTOK, 256, 0, stream>>>(h, g1 + l*HDIM, beta1 + l*HDIM, hb);
        // FF1 + gelu: [4096,768] @ [768,3072] -> bf16
        k_gemm_mfma<128, 128, 2, 3><<<dim3(FFDIM/128, MTOK/128), 256, 0, stream>>>(
            hb, w1T_l, b1 + l*FFDIM, nullptr, nullptr, mid, HDIM, FFDIM);
        // FF2: [4096,3072] @ [3072,768], residual-add into h
        k_gemm_mfma<128, 64, 3, 3><<<dim3(HDIM/64, MTOK/128), 256, 0, stream>>>(
            mid, w2T_l, b2 + l*HDIM, nullptr, nullptr, h, FFDIM, HDIM);
        k_ln<<<MTOK, 256, 0, stream>>>(h, g2 + l*HDIM, beta2 + l*HDIM, hb);
    }

    // pool scratch lives in tbuf (dead during the layer loop)
    float* ps      = tbuf;                 // [B][SEQ] probs
    float* partial = tbuf + BATCH * SEQ;   // [B][16][HDIM] partial sums
    k_pool_score  <<<MTOK / 4, 256, 0, stream>>>(h, aw, ps);
    k_pool_softmax<<<BATCH, 1024, 0, stream>>>(ps);
    k_pool_reduce <<<dim3(BATCH, 16), 256, 0, stream>>>(h, ps, partial);
    k_pool_final  <<<BATCH, 256, 0, stream>>>(partial, Wc, bc, (float*)d_out);
}

// Round 12
// 2650.253 us; speedup vs baseline: 1.1869x; 1.1869x over previous
//
#include <hip/hip_runtime.h>
#include <hip/hip_bf16.h>

#define LAYERS 12
#define NHEAD  12
#define DHEAD  64
#define HDIM   768
#define FFDIM  3072
#define SEQ    1024
#define BATCH  4
#define WINSZ  256
#define MTOK   (BATCH*SEQ)          // 4096
#define PLANE  ((size_t)MTOK*HDIM)  // q/k/v plane elems: B*NH*S*DH = 3,145,728

typedef unsigned short u16;
typedef unsigned int   u32;

using f32x4  = __attribute__((ext_vector_type(4))) float;
using bf16x8 = __attribute__((ext_vector_type(8))) short;

__device__ __forceinline__ float bflo(u32 u){ union{u32 i;float f;}x; x.i = u << 16; return x.f; }
__device__ __forceinline__ float bfhi(u32 u){ union{u32 i;float f;}x; x.i = u & 0xffff0000u; return x.f; }
__device__ __forceinline__ u16 f2bf(float f){
    union{float f;u32 u;}x; x.f = f;
    u32 r = x.u + 0x7fffu + ((x.u >> 16) & 1u);   // RTNE
    return (u16)(r >> 16);
}
__device__ __forceinline__ void gload16(const u16* g, u16* l) {
    __builtin_amdgcn_global_load_lds(
        (const __attribute__((address_space(1))) u32*)g,
        (__attribute__((address_space(3))) u32*)l, 16, 0, 0);
}
// XCD-aware chunked block remap (bijective when total % 8 == 0):
// XCD x receives the contiguous flat range [x*total/8, (x+1)*total/8).
__device__ __forceinline__ int xcd_swz(int flat, int total) {
    return (flat & 7) * (total >> 3) + (flat >> 3);
}

// ---------------- reductions ----------------
__device__ __forceinline__ float wave_sum(float v) {
#pragma unroll
    for (int o = 32; o > 0; o >>= 1) v += __shfl_down(v, o, 64);
    return v;
}
__device__ __forceinline__ float wave_max(float v) {
#pragma unroll
    for (int o = 32; o > 0; o >>= 1) v = fmaxf(v, __shfl_down(v, o, 64));
    return v;
}
__device__ __forceinline__ float blk_sum256(float v, float* sm) {
    v = wave_sum(v);
    int lane = threadIdx.x & 63, w = threadIdx.x >> 6;
    __syncthreads();
    if (lane == 0) sm[w] = v;
    __syncthreads();
    return sm[0] + sm[1] + sm[2] + sm[3];
}
__device__ __forceinline__ float blk_sum1024(float v, float* sm) {
    v = wave_sum(v);
    int lane = threadIdx.x & 63, w = threadIdx.x >> 6;
    __syncthreads();
    if (lane == 0) sm[w] = v;
    __syncthreads();
    float r = 0.f;
#pragma unroll
    for (int i = 0; i < 16; i++) r += sm[i];
    return r;
}
__device__ __forceinline__ float blk_max1024(float v, float* sm) {
    v = wave_max(v);
    int lane = threadIdx.x & 63, w = threadIdx.x >> 6;
    __syncthreads();
    if (lane == 0) sm[w] = v;
    __syncthreads();
    float r = -1e30f;
#pragma unroll
    for (int i = 0; i < 16; i++) r = fmaxf(r, sm[i]);
    return r;
}

// ---------------- embedding + LN (writes h fp32 and hb bf16) ----------------
__global__ __launch_bounds__(256) void k_embed_ln(
    const float* __restrict__ WE, const float* __restrict__ PE,
    const float* __restrict__ g, const float* __restrict__ bta,
    const int* __restrict__ ids, float* __restrict__ h, u16* __restrict__ hb)
{
    __shared__ float sm[4];
    int tok = blockIdx.x;
    int s = tok & (SEQ - 1);
    int id = ids[tok];
    int tt = threadIdx.x;
    float4 x = make_float4(0.f, 0.f, 0.f, 0.f);
    if (tt < HDIM / 4) {
        float4 a = ((const float4*)(WE + (size_t)id * HDIM))[tt];
        float4 b = ((const float4*)(PE + (size_t)s * HDIM))[tt];
        x = make_float4(a.x + b.x, a.y + b.y, a.z + b.z, a.w + b.w);
    }
    float s1 = blk_sum256(x.x + x.y + x.z + x.w, sm);
    float s2 = blk_sum256(x.x*x.x + x.y*x.y + x.z*x.z + x.w*x.w, sm);
    float mean = s1 * (1.f / HDIM);
    float var  = s2 * (1.f / HDIM) - mean * mean;
    float inv  = rsqrtf(var + 1e-5f);
    if (tt < HDIM / 4) {
        float4 gg = ((const float4*)g)[tt];
        float4 bb = ((const float4*)bta)[tt];
        float4 o;
        o.x = (x.x - mean) * inv * gg.x + bb.x;
        o.y = (x.y - mean) * inv * gg.y + bb.y;
        o.z = (x.z - mean) * inv * gg.z + bb.z;
        o.w = (x.w - mean) * inv * gg.w + bb.w;
        ((float4*)(h + (size_t)tok * HDIM))[tt] = o;
        uint2 pk;
        pk.x = (u32)f2bf(o.x) | ((u32)f2bf(o.y) << 16);
        pk.y = (u32)f2bf(o.z) | ((u32)f2bf(o.w) << 16);
        ((uint2*)(hb + (size_t)tok * HDIM))[tt] = pk;
    }
}

// ---------------- residual add + LN (h fp32 in place, hb bf16 out) ----------------
__global__ __launch_bounds__(256) void k_addln(
    float* __restrict__ h, const float* __restrict__ t,
    const float* __restrict__ g, const float* __restrict__ bta, u16* __restrict__ hb)
{
    __shared__ float sm[4];
    int tok = blockIdx.x;
    int tt = threadIdx.x;
    float4 x = make_float4(0.f, 0.f, 0.f, 0.f);
    if (tt < HDIM / 4) {
        float4 a = ((const float4*)(h + (size_t)tok * HDIM))[tt];
        float4 b = ((const float4*)(t + (size_t)tok * HDIM))[tt];
        x = make_float4(a.x + b.x, a.y + b.y, a.z + b.z, a.w + b.w);
    }
    float s1 = blk_sum256(x.x + x.y + x.z + x.w, sm);
    float s2 = blk_sum256(x.x*x.x + x.y*x.y + x.z*x.z + x.w*x.w, sm);
    float mean = s1 * (1.f / HDIM);
    float var  = s2 * (1.f / HDIM) - mean * mean;
    float inv  = rsqrtf(var + 1e-5f);
    if (tt < HDIM / 4) {
        float4 gg = ((const float4*)g)[tt];
        float4 bb = ((const float4*)bta)[tt];
        float4 o;
        o.x = (x.x - mean) * inv * gg.x + bb.x;
        o.y = (x.y - mean) * inv * gg.y + bb.y;
        o.z = (x.z - mean) * inv * gg.z + bb.z;
        o.w = (x.w - mean) * inv * gg.w + bb.w;
        ((float4*)(h + (size_t)tok * HDIM))[tt] = o;
        uint2 pk;
        pk.x = (u32)f2bf(o.x) | ((u32)f2bf(o.y) << 16);
        pk.y = (u32)f2bf(o.z) | ((u32)f2bf(o.w) << 16);
        ((uint2*)(hb + (size_t)tok * HDIM))[tt] = pk;
    }
}

// ---------------- transpose + fp32->bf16: W[K][N] -> dst[N][K] ----------------
// grid (N/32, K/32, nlayers), 256 threads; ss/ds = per-layer element strides
__global__ __launch_bounds__(256) void k_cvtT(
    const float* __restrict__ W, u16* __restrict__ dst, int K, int N,
    size_t ss, size_t ds)
{
    __shared__ float t[32][33];
    W   += (size_t)blockIdx.z * ss;
    dst += (size_t)blockIdx.z * ds;
    int n0 = blockIdx.x * 32, k0 = blockIdx.y * 32;
    int c = threadIdx.x & 31, r8 = threadIdx.x >> 5;
#pragma unroll
    for (int p = 0; p < 4; p++) {
        int k = r8 + p * 8;
        t[k][c] = W[(size_t)(k0 + k) * N + n0 + c];
    }
    __syncthreads();
#pragma unroll
    for (int p = 0; p < 2; p++) {
        int idx = threadIdx.x + p * 256;       // 0..511 over 32 n-rows x 16 k-pairs
        int n = idx >> 4, kp = idx & 15;
        float a = t[kp*2][n], b = t[kp*2+1][n];
        u32 pk = (u32)f2bf(a) | ((u32)f2bf(b) << 16);
        u32* d = (u32*)(dst + (size_t)(n0 + n) * K + k0);
        d[kp] = pk;
    }
}

// ---------------- MFMA GEMM: C[M,N] = A[M,K](bf16) @ BT[N,K]^T(bf16) ----------------
// NS BK=32 K-subtiles staged per barrier pair (LDS [NS][BM][32]). NS=2 verified
// optimal: NS=3 (48KB LDS at 128^2) cut occupancy 4->3 blocks/CU and REGRESSED
// (round 9: +370us). Blocks remapped via xcd_swz for per-XCD L2 panel locality.
// MODE 0: C fp32 [M,N] (+bias b0)
// MODE 1: QKV split -> bf16 planes [3][B,NH,S,DH], biases b0/b1/b2
// MODE 2: GELU -> bf16 [M,N]
template<int BM, int BN, int MODE, int NS>
__global__ __launch_bounds__(256) void k_gemm_mfma(
    const u16* __restrict__ A, const u16* __restrict__ BT,
    const float* __restrict__ b0, const float* __restrict__ b1, const float* __restrict__ b2,
    void* __restrict__ C, int K, int N)
{
    __shared__ u16 As[NS * BM * 32];
    __shared__ u16 Bs[NS * BN * 32];
    const int tid = threadIdx.x, lane = tid & 63, w = tid >> 6;
    int flat = blockIdx.y * gridDim.x + blockIdx.x;
    flat = xcd_swz(flat, gridDim.x * gridDim.y);
    const int bm = (flat / gridDim.x) * BM, bn = (flat % gridDim.x) * BN;
    constexpr int MT = BM / 32, NT = BN / 32;      // mfma tiles per wave
    constexpr int AR = BM / 4, BR = BN / 4;        // staging rows per wave
    constexpr int AI = AR / 16, BI = BR / 16;      // lds-dma instrs per wave per subtile
    const int wm = (w & 1) * (BM / 2), wn = (w >> 1) * (BN / 2);

    f32x4 acc[MT][NT];
#pragma unroll
    for (int mi = 0; mi < MT; mi++)
#pragma unroll
        for (int ni = 0; ni < NT; ni++) acc[mi][ni] = (f32x4){0.f, 0.f, 0.f, 0.f};

    const u16* ag = A  + (size_t)(bm + w * AR + (lane >> 2)) * K + (lane & 3) * 8;
    const u16* bg = BT + (size_t)(bn + w * BR + (lane >> 2)) * K + (lane & 3) * 8;
    u16* al = As + w * AR * 32;
    u16* bl = Bs + w * BR * 32;
    const int fr = lane & 15, fq = (lane >> 4) * 8;

    for (int k0 = 0; k0 < K; k0 += 32 * NS) {
#pragma unroll
        for (int s = 0; s < NS; s++) {
#pragma unroll
            for (int i = 0; i < AI; i++)
                gload16(ag + (size_t)i * 16 * K + k0 + s * 32, al + s * BM * 32 + i * 512);
#pragma unroll
            for (int i = 0; i < BI; i++)
                gload16(bg + (size_t)i * 16 * K + k0 + s * 32, bl + s * BN * 32 + i * 512);
        }
        __syncthreads();
#pragma unroll
        for (int s = 0; s < NS; s++) {
            bf16x8 af[MT], bf[NT];
#pragma unroll
            for (int mi = 0; mi < MT; mi++)
                af[mi] = *(const bf16x8*)(As + s * BM * 32 + (wm + mi * 16 + fr) * 32 + fq);
#pragma unroll
            for (int ni = 0; ni < NT; ni++)
                bf[ni] = *(const bf16x8*)(Bs + s * BN * 32 + (wn + ni * 16 + fr) * 32 + fq);
#pragma unroll
            for (int mi = 0; mi < MT; mi++)
#pragma unroll
                for (int ni = 0; ni < NT; ni++)
                    acc[mi][ni] = __builtin_amdgcn_mfma_f32_16x16x32_bf16(af[mi], bf[ni], acc[mi][ni], 0, 0, 0);
        }
        __syncthreads();
    }

#pragma unroll
    for (int mi = 0; mi < MT; mi++) {
        int m_base = bm + wm + mi * 16 + (lane >> 4) * 4;
#pragma unroll
        for (int ni = 0; ni < NT; ni++) {
            int n_g = bn + wn + ni * 16 + (lane & 15);
            const float* bp = b0; int nn = n_g; int which = 0;
            if (MODE == 1) {
                if (n_g >= 1536)      { bp = b2; nn = n_g - 1536; which = 2; }
                else if (n_g >= 768)  { bp = b1; nn = n_g - 768;  which = 1; }
            }
            float bias = bp[nn];
#pragma unroll
            for (int r = 0; r < 4; r++) {
                int m_g = m_base + r;
                float val = acc[mi][ni][r] + bias;
                if (MODE == 0) {
                    ((float*)C)[(size_t)m_g * N + n_g] = val;
                } else if (MODE == 1) {
                    int bb = m_g >> 10, ss = m_g & 1023;
                    int hh = nn >> 6, dd = nn & 63;
                    ((u16*)C)[(size_t)which * PLANE + (((size_t)bb * NHEAD + hh) * SEQ + ss) * DHEAD + dd] = f2bf(val);
                } else {
                    val = 0.5f * val * (1.f + erff(val * 0.70710678118f));
                    ((u16*)C)[(size_t)m_g * N + n_g] = f2bf(val);
                }
            }
        }
    }
}

// ---------------- MFMA banded local attention ----------------
// One block per (b, h, 64-row q tile). 4 waves; wave w owns q rows [w*16, w*16+16).
// Keys iterated in 9 chunks of 64 covering span [q0-256, q0+319].
// QK^T and PV both via mfma_f32_16x16x32_bf16; online softmax held in registers
// (each lane owns 4 q rows; row-reduce = shfl_xor butterfly over the 16 key lanes).
// LDS rows padded to 72 u16 (144 B). Blocks xcd_swz-remapped so same-head q-tiles
// (overlapping K/V windows) co-locate on one XCD's L2.
#define PADW 72
__global__ __launch_bounds__(256) void k_attn_mfma(
    const u16* __restrict__ qkv, const int* __restrict__ mask, u16* __restrict__ abuf)
{
    __shared__ u16 Qs[64 * PADW];
    __shared__ u16 Ks[64 * PADW];
    __shared__ u16 Vt[64 * PADW];   // transposed: [dh][key]
    __shared__ u16 Ps[64 * PADW];   // probs bf16: [q][key]
    __shared__ int ms[64];
    const int tid = threadIdx.x, lane = tid & 63, w = tid >> 6;
    int blk = xcd_swz(blockIdx.x, gridDim.x);
    int qt = blk & 15;
    int hh = (blk >> 4) % NHEAD;
    int b  = blk / (16 * NHEAD);
    int q0 = qt * 64;

    const u16* qp = qkv + ((size_t)b * NHEAD + hh) * SEQ * DHEAD;
    const u16* kp = qp + PLANE;
    const u16* vp = qp + 2 * PLANE;

    // stage Q tile [64][64] once
#pragma unroll
    for (int it = 0; it < 2; it++) {
        int idx = tid + it * 256;            // 512 segs = 64 rows x 8 col-segs
        int r = idx >> 3, c8 = (idx & 7) * 8;
        uint4 u = *(const uint4*)(qp + (size_t)(q0 + r) * DHEAD + c8);
        *(uint4*)(Qs + r * PADW + c8) = u;
    }

    const int fr = lane & 15, g4 = (lane >> 4) * 4, fq = (lane >> 4) * 8;
    const int wq = w * 16;
    const int qpos = q0 + wq + g4;           // +r gives this lane's q rows

    f32x4 o[4];                               // out acc: [dh tile][q row r]
#pragma unroll
    for (int d = 0; d < 4; d++) o[d] = (f32x4){0.f, 0.f, 0.f, 0.f};
    float mr[4], ll[4];
#pragma unroll
    for (int r = 0; r < 4; r++) { mr[r] = -1e9f; ll[r] = 0.f; }

    __syncthreads();
    bf16x8 aq[2];                             // Q A-frags, persist across chunks
#pragma unroll
    for (int ks = 0; ks < 2; ks++)
        aq[ks] = *(const bf16x8*)(Qs + (wq + fr) * PADW + ks * 32 + fq);

    for (int ch = 0; ch < 9; ch++) {
        int kbase = q0 - 256 + ch * 64;
        __syncthreads();                      // prev chunk's PV reads done
        // stage K rows [64][64]
#pragma unroll
        for (int it = 0; it < 2; it++) {
            int idx = tid + it * 256;
            int r = idx >> 3, c8 = (idx & 7) * 8;
            int kq = kbase + r;
            uint4 u = (kq >= 0 && kq < SEQ)
                ? *(const uint4*)(kp + (size_t)kq * DHEAD + c8)
                : make_uint4(0u, 0u, 0u, 0u);
            *(uint4*)(Ks + r * PADW + c8) = u;
        }
        // stage V transposed: thread handles key r = tid>>2, dh seg (tid&3)*16
        {
            int r = tid >> 2, sg = (tid & 3) * 16;
            int kq = kbase + r;
            uint4 u0 = make_uint4(0u,0u,0u,0u), u1 = u0;
            if (kq >= 0 && kq < SEQ) {
                const uint4* vr = (const uint4*)(vp + (size_t)kq * DHEAD + sg);
                u0 = vr[0]; u1 = vr[1];
            }
            u32 ww[8] = {u0.x, u0.y, u0.z, u0.w, u1.x, u1.y, u1.z, u1.w};
#pragma unroll
            for (int j = 0; j < 8; j++) {
                Vt[(sg + 2*j    ) * PADW + r] = (u16)(ww[j] & 0xffffu);
                Vt[(sg + 2*j + 1) * PADW + r] = (u16)(ww[j] >> 16);
            }
        }
        if (tid < 64) {
            int kq = kbase + tid;
            ms[tid] = (kq >= 0 && kq < SEQ) ? mask[b * SEQ + kq] : 0;
        }
        __syncthreads();

        // QK^T: s[nt][r] = score[q = wq+g4+r][key = nt*16+fr]
        f32x4 s[4];
#pragma unroll
        for (int nt = 0; nt < 4; nt++) s[nt] = (f32x4){0.f, 0.f, 0.f, 0.f};
#pragma unroll
        for (int nt = 0; nt < 4; nt++)
#pragma unroll
            for (int ks = 0; ks < 2; ks++) {
                bf16x8 bk = *(const bf16x8*)(Ks + (nt*16 + fr) * PADW + ks*32 + fq);
                s[nt] = __builtin_amdgcn_mfma_f32_16x16x32_bf16(aq[ks], bk, s[nt], 0, 0, 0);
            }

        // scale + band/mask, per-lane chunk max
        float mloc[4];
#pragma unroll
        for (int r = 0; r < 4; r++) mloc[r] = -1e9f;
#pragma unroll
        for (int nt = 0; nt < 4; nt++) {
            int kpos = kbase + nt*16 + fr;
            int msv = ms[nt*16 + fr];
#pragma unroll
            for (int r = 0; r < 4; r++) {
                int dq = kpos - (qpos + r);
                bool ok = (dq >= -WINSZ) && (dq <= WINSZ) && (msv != 0);
                float sv = ok ? s[nt][r] * 0.125f : -1e9f;
                s[nt][r] = sv;
                mloc[r] = fmaxf(mloc[r], sv);
            }
        }
        // butterfly max over the 16 key lanes
#pragma unroll
        for (int mk = 1; mk < 16; mk <<= 1)
#pragma unroll
            for (int r = 0; r < 4; r++)
                mloc[r] = fmaxf(mloc[r], __shfl_xor(mloc[r], mk, 64));

        float sc4[4], psum[4];
#pragma unroll
        for (int r = 0; r < 4; r++) {
            float mn = fmaxf(mr[r], mloc[r]);
            sc4[r] = __expf(mr[r] - mn);
            mr[r] = mn;
            psum[r] = 0.f;
        }
        // p = exp(s - m), write bf16 P to LDS (rows owned by this wave only)
#pragma unroll
        for (int nt = 0; nt < 4; nt++)
#pragma unroll
            for (int r = 0; r < 4; r++) {
                float p = (s[nt][r] > -1e8f) ? __expf(s[nt][r] - mr[r]) : 0.f;
                psum[r] += p;
                Ps[(wq + g4 + r) * PADW + nt*16 + fr] = f2bf(p);
            }
        // butterfly sum over key lanes
#pragma unroll
        for (int mk = 1; mk < 16; mk <<= 1)
#pragma unroll
            for (int r = 0; r < 4; r++)
                psum[r] += __shfl_xor(psum[r], mk, 64);

        f32x4 scv = (f32x4){sc4[0], sc4[1], sc4[2], sc4[3]};
#pragma unroll
        for (int r = 0; r < 4; r++) ll[r] = ll[r] * sc4[r] + psum[r];
#pragma unroll
        for (int d = 0; d < 4; d++) o[d] *= scv;

        // PV: o[d] += P[q,keys] @ Vt[dh,keys]^T  (same-wave LDS write->read, in-order)
#pragma unroll
        for (int ks = 0; ks < 2; ks++) {
            bf16x8 ap = *(const bf16x8*)(Ps + (wq + fr) * PADW + ks*32 + fq);
#pragma unroll
            for (int d = 0; d < 4; d++) {
                bf16x8 bv8 = *(const bf16x8*)(Vt + (d*16 + fr) * PADW + ks*32 + fq);
                o[d] = __builtin_amdgcn_mfma_f32_16x16x32_bf16(ap, bv8, o[d], 0, 0, 0);
            }
        }
    }

    // epilogue: normalize and store bf16 to abuf[B,S,H]
#pragma unroll
    for (int r = 0; r < 4; r++) {
        float inv = 1.f / ll[r];
        u16* orow = abuf + ((size_t)(b * SEQ + q0 + wq + g4 + r)) * HDIM + hh * DHEAD;
#pragma unroll
        for (int d = 0; d < 4; d++)
            orow[d*16 + fr] = f2bf(o[d][r] * inv);
    }
}

// ---------------- attention-pool head (parallelized) ----------------
// Phase A: sc[tok] = h[tok]·aw — one wave per token, grid MTOK/4 x 256
__global__ __launch_bounds__(256) void k_pool_score(
    const float* __restrict__ h, const float* __restrict__ aw, float* __restrict__ sc)
{
    int tok = blockIdx.x * 4 + (threadIdx.x >> 6);
    int lane = threadIdx.x & 63;
    const float4* hr = (const float4*)(h + (size_t)tok * HDIM);
    const float4* ar = (const float4*)aw;
    float acc = 0.f;
#pragma unroll
    for (int i = 0; i < 3; i++) {
        int c = lane + i * 64;               // 192 float4 per row
        float4 x = hr[c], a = ar[c];
        acc += x.x*a.x + x.y*a.y + x.z*a.z + x.w*a.w;
    }
    acc = wave_sum(acc);
    if (lane == 0) sc[tok] = acc;
}

// Phase B: softmax over s per batch — grid B x 1024; sc in-place -> probs
__global__ __launch_bounds__(1024) void k_pool_softmax(float* __restrict__ sc)
{
    __shared__ float red[16];
    int b = blockIdx.x;
    float v = sc[b * SEQ + threadIdx.x];
    float mx = blk_max1024(v, red);
    float e = __expf(v - mx);
    float tot = blk_sum1024(e, red);
    sc[b * SEQ + threadIdx.x] = e / tot;
}

// Phase C: partial weighted sums over 64-row s-slices — grid (B,16) x 256
// partial[b][j][d] = sum_{s in slice j} h[b][s][d] * ps[b][s]
__global__ __launch_bounds__(256) void k_pool_reduce(
    const float* __restrict__ h, const float* __restrict__ ps, float* __restrict__ partial)
{
    int b = blockIdx.x, j = blockIdx.y;
    int tid = threadIdx.x;
    const float* hb = h + ((size_t)b * SEQ + j * 64) * HDIM;
    const float* pp = ps + b * SEQ + j * 64;
    float a0 = 0.f, a1 = 0.f, a2 = 0.f;
    for (int s = 0; s < 64; s++) {
        float p = pp[s];
        const float* row = hb + (size_t)s * HDIM;
        a0 = fmaf(row[tid],       p, a0);
        a1 = fmaf(row[tid + 256], p, a1);
        a2 = fmaf(row[tid + 512], p, a2);
    }
    float* outp = partial + ((size_t)b * 16 + j) * HDIM;
    outp[tid] = a0; outp[tid + 256] = a1; outp[tid + 512] = a2;
}

// Phase D: reduce 16 partials, dot with Wc — grid B x 256
__global__ __launch_bounds__(256) void k_pool_final(
    const float* __restrict__ partial, const float* __restrict__ Wc,
    const float* __restrict__ bc, float* __restrict__ out)
{
    __shared__ float sm[4];
    int b = blockIdx.x, tid = threadIdx.x;
    float acc = 0.f;
#pragma unroll
    for (int dd = 0; dd < 3; dd++) {
        int d = tid + dd * 256;
        float pd = 0.f;
#pragma unroll
        for (int j = 0; j < 16; j++)
            pd += partial[((size_t)b * 16 + j) * HDIM + d];
        acc = fmaf(pd, Wc[d], acc);
    }
    float total = blk_sum256(acc, sm);
    if (tid == 0) out[b] = total + bc[0];
}

// ---------------- launcher ----------------
extern "C" void kernel_launch(void* const* d_in, const int* in_sizes, int n_in,
                              void* d_out, int out_size, void* d_ws, size_t ws_size,
                              hipStream_t stream)
{
    const float* WE    = (const float*)d_in[0];
    const float* PE    = (const float*)d_in[1];
    const float* Eg    = (const float*)d_in[2];
    const float* Eb    = (const float*)d_in[3];
    const float* Wq    = (const float*)d_in[4];
    const float* bq    = (const float*)d_in[5];
    const float* Wk    = (const float*)d_in[6];
    const float* bk    = (const float*)d_in[7];
    const float* Wv    = (const float*)d_in[8];
    const float* bv    = (const float*)d_in[9];
    const float* Wo    = (const float*)d_in[10];
    const float* bo    = (const float*)d_in[11];
    const float* g1    = (const float*)d_in[12];
    const float* beta1 = (const float*)d_in[13];
    const float* W1    = (const float*)d_in[14];
    const float* b1    = (const float*)d_in[15];
    const float* W2    = (const float*)d_in[16];
    const float* b2    = (const float*)d_in[17];
    const float* g2    = (const float*)d_in[18];
    const float* beta2 = (const float*)d_in[19];
    const float* aw    = (const float*)d_in[20];
    const float* Wc    = (const float*)d_in[21];
    const float* bc    = (const float*)d_in[22];
    const int* ids     = (const int*)d_in[23];
    const int* msk     = (const int*)d_in[24];

    char* base = (char*)d_ws;
    float* h    = (float*)base;                               base += (size_t)MTOK * HDIM * 4;   // 12.6MB
    float* tbuf = (float*)base;                               base += (size_t)MTOK * HDIM * 4;   // 12.6MB
    u16*   hb   = (u16*)base;                                 base += (size_t)MTOK * HDIM * 2;   // 6.3MB
    u16*   X    = (u16*)base;                                 base += (size_t)MTOK * FFDIM * 2;  // 25.2MB
    u16*   qkv  = X;                                          // 3 planes of PLANE
    u16*   abuf = X + 3 * PLANE;                              // [B,S,H] bf16
    u16*   mid  = X;                                          // FF1 out aliases qkv/abuf (dead)

    // weight buffers: if workspace allows, convert ALL layers once up front
    const size_t sQKV = (size_t)2304 * HDIM;   // per-layer elems
    const size_t sWO  = (size_t)HDIM * HDIM;
    const size_t sW1  = (size_t)FFDIM * HDIM;
    const size_t sW2  = (size_t)HDIM * FFDIM;
    size_t fixed = (size_t)(base - (char*)d_ws);
    size_t all_bytes = fixed + (size_t)LAYERS * (sQKV + sWO + sW1 + sW2) * 2;
    bool wsall = ws_size >= all_bytes;
    int NL = wsall ? LAYERS : 1;
    u16* wqkvT = (u16*)base;
    u16* woT   = wqkvT + sQKV * NL;
    u16* w1T   = woT   + sWO  * NL;
    u16* w2T   = w1T   + sW1  * NL;

    k_embed_ln<<<MTOK, 256, 0, stream>>>(WE, PE, Eg, Eb, ids, h, hb);

    if (wsall) {
        k_cvtT<<<dim3(24, 24, LAYERS), 256, 0, stream>>>(Wq, wqkvT,                     HDIM, HDIM, (size_t)HDIM*HDIM, sQKV);
        k_cvtT<<<dim3(24, 24, LAYERS), 256, 0, stream>>>(Wk, wqkvT + (size_t)HDIM*HDIM, HDIM, HDIM, (size_t)HDIM*HDIM, sQKV);
        k_cvtT<<<dim3(24, 24, LAYERS), 256, 0, stream>>>(Wv, wqkvT + (size_t)2*HDIM*HDIM, HDIM, HDIM, (size_t)HDIM*HDIM, sQKV);
        k_cvtT<<<dim3(24, 24, LAYERS), 256, 0, stream>>>(Wo, woT, HDIM, HDIM, (size_t)HDIM*HDIM, sWO);
        k_cvtT<<<dim3(96, 24, LAYERS), 256, 0, stream>>>(W1, w1T, HDIM, FFDIM, (size_t)HDIM*FFDIM, sW1);
        k_cvtT<<<dim3(24, 96, LAYERS), 256, 0, stream>>>(W2, w2T, FFDIM, HDIM, (size_t)FFDIM*HDIM, sW2);
    }

    for (int l = 0; l < LAYERS; l++) {
        u16* wqkvT_l = wqkvT + (wsall ? (size_t)l * sQKV : 0);
        u16* woT_l   = woT   + (wsall ? (size_t)l * sWO  : 0);
        u16* w1T_l   = w1T   + (wsall ? (size_t)l * sW1  : 0);
        u16* w2T_l   = w2T   + (wsall ? (size_t)l * sW2  : 0);

        if (!wsall) {
            const float* Wql = Wq + (size_t)l * HDIM * HDIM;
            const float* Wkl = Wk + (size_t)l * HDIM * HDIM;
            const float* Wvl = Wv + (size_t)l * HDIM * HDIM;
            const float* Wol = Wo + (size_t)l * HDIM * HDIM;
            const float* W1l = W1 + (size_t)l * HDIM * FFDIM;
            const float* W2l = W2 + (size_t)l * FFDIM * HDIM;
            k_cvtT<<<dim3(24, 24), 256, 0, stream>>>(Wql, wqkvT_l,                      HDIM, HDIM, 0, 0);
            k_cvtT<<<dim3(24, 24), 256, 0, stream>>>(Wkl, wqkvT_l + (size_t)HDIM*HDIM,  HDIM, HDIM, 0, 0);
            k_cvtT<<<dim3(24, 24), 256, 0, stream>>>(Wvl, wqkvT_l + (size_t)2*HDIM*HDIM,HDIM, HDIM, 0, 0);
            k_cvtT<<<dim3(24, 24), 256, 0, stream>>>(Wol, woT_l, HDIM, HDIM, 0, 0);
            k_cvtT<<<dim3(96, 24), 256, 0, stream>>>(W1l, w1T_l, HDIM, FFDIM, 0, 0);
            k_cvtT<<<dim3(24, 96), 256, 0, stream>>>(W2l, w2T_l, FFDIM, HDIM, 0, 0);
        }

        // QKV fused: [4096,768] @ [768,2304]
        k_gemm_mfma<128, 128, 1, 2><<<dim3(2304/128, MTOK/128), 256, 0, stream>>>(
            hb, wqkvT_l, bq + l*HDIM, bk + l*HDIM, bv + l*HDIM, qkv, HDIM, 2304);
        // banded attention (MFMA)
        k_attn_mfma<<<BATCH * NHEAD * (SEQ/64), 256, 0, stream>>>(qkv, msk, abuf);
        // attn out proj: [4096,768] @ [768,768] -> fp32
        k_gemm_mfma<128, 64, 0, 2><<<dim3(HDIM/64, MTOK/128), 256, 0, stream>>>(
            abuf, woT_l, bo + l*HDIM, nullptr, nullptr, tbuf, HDIM, HDIM);
        k_addln<<<MTOK, 256, 0, stream>>>(h, tbuf, g1 + l*HDIM, beta1 + l*HDIM, hb);
        // FF1 + gelu: [4096,768] @ [768,3072] -> bf16
        k_gemm_mfma<128, 128, 2, 2><<<dim3(FFDIM/128, MTOK/128), 256, 0, stream>>>(
            hb, w1T_l, b1 + l*FFDIM, nullptr, nullptr, mid, HDIM, FFDIM);
        // FF2: [4096,3072] @ [3072,768] -> fp32
        k_gemm_mfma<128, 64, 0, 2><<<dim3(HDIM/64, MTOK/128), 256, 0, stream>>>(
            mid, w2T_l, b2 + l*HDIM, nullptr, nullptr, tbuf, FFDIM, HDIM);
        k_addln<<<MTOK, 256, 0, stream>>>(h, tbuf, g2 + l*HDIM, beta2 + l*HDIM, hb);
    }

    // pool scratch lives in tbuf (dead after the layer loop)
    float* ps      = tbuf;                 // [B][SEQ] probs
    float* partial = tbuf + BATCH * SEQ;   // [B][16][HDIM] partial sums
    k_pool_score  <<<MTOK / 4, 256, 0, stream>>>(h, aw, ps);
    k_pool_softmax<<<BATCH, 1024, 0, stream>>>(ps);
    k_pool_reduce <<<dim3(BATCH, 16), 256, 0, stream>>>(h, ps, partial);
    k_pool_final  <<<BATCH, 256, 0, stream>>>(partial, Wc, bc, (float*)d_out);
}

// Round 13
// 2576.148 us; speedup vs baseline: 1.2210x; 1.0288x over previous
//
#include <hip/hip_runtime.h>
#include <hip/hip_bf16.h>

#define LAYERS 12
#define NHEAD  12
#define DHEAD  64
#define HDIM   768
#define FFDIM  3072
#define SEQ    1024
#define BATCH  4
#define WINSZ  256
#define MTOK   (BATCH*SEQ)          // 4096
#define PLANE  ((size_t)MTOK*HDIM)  // q/k/v plane elems: B*NH*S*DH = 3,145,728

typedef unsigned short u16;
typedef unsigned int   u32;

using f32x4  = __attribute__((ext_vector_type(4))) float;
using bf16x8 = __attribute__((ext_vector_type(8))) short;

__device__ __forceinline__ float bflo(u32 u){ union{u32 i;float f;}x; x.i = u << 16; return x.f; }
__device__ __forceinline__ float bfhi(u32 u){ union{u32 i;float f;}x; x.i = u & 0xffff0000u; return x.f; }
__device__ __forceinline__ u16 f2bf(float f){
    union{float f;u32 u;}x; x.f = f;
    u32 r = x.u + 0x7fffu + ((x.u >> 16) & 1u);   // RTNE
    return (u16)(r >> 16);
}
__device__ __forceinline__ void gload16(const u16* g, u16* l) {
    __builtin_amdgcn_global_load_lds(
        (const __attribute__((address_space(1))) u32*)g,
        (__attribute__((address_space(3))) u32*)l, 16, 0, 0);
}
// XCD-aware chunked block remap (bijective when total % 8 == 0):
// XCD x receives the contiguous flat range [x*total/8, (x+1)*total/8).
__device__ __forceinline__ int xcd_swz(int flat, int total) {
    return (flat & 7) * (total >> 3) + (flat >> 3);
}

// ---------------- reductions ----------------
__device__ __forceinline__ float wave_sum(float v) {
#pragma unroll
    for (int o = 32; o > 0; o >>= 1) v += __shfl_down(v, o, 64);
    return v;
}
__device__ __forceinline__ float wave_max(float v) {
#pragma unroll
    for (int o = 32; o > 0; o >>= 1) v = fmaxf(v, __shfl_down(v, o, 64));
    return v;
}
__device__ __forceinline__ float blk_sum256(float v, float* sm) {
    v = wave_sum(v);
    int lane = threadIdx.x & 63, w = threadIdx.x >> 6;
    __syncthreads();
    if (lane == 0) sm[w] = v;
    __syncthreads();
    return sm[0] + sm[1] + sm[2] + sm[3];
}
__device__ __forceinline__ float blk_sum1024(float v, float* sm) {
    v = wave_sum(v);
    int lane = threadIdx.x & 63, w = threadIdx.x >> 6;
    __syncthreads();
    if (lane == 0) sm[w] = v;
    __syncthreads();
    float r = 0.f;
#pragma unroll
    for (int i = 0; i < 16; i++) r += sm[i];
    return r;
}
__device__ __forceinline__ float blk_max1024(float v, float* sm) {
    v = wave_max(v);
    int lane = threadIdx.x & 63, w = threadIdx.x >> 6;
    __syncthreads();
    if (lane == 0) sm[w] = v;
    __syncthreads();
    float r = -1e30f;
#pragma unroll
    for (int i = 0; i < 16; i++) r = fmaxf(r, sm[i]);
    return r;
}

// ---------------- embedding + LN (writes h fp32 and hb bf16) ----------------
__global__ __launch_bounds__(256) void k_embed_ln(
    const float* __restrict__ WE, const float* __restrict__ PE,
    const float* __restrict__ g, const float* __restrict__ bta,
    const int* __restrict__ ids, float* __restrict__ h, u16* __restrict__ hb)
{
    __shared__ float sm[4];
    int tok = blockIdx.x;
    int s = tok & (SEQ - 1);
    int id = ids[tok];
    int tt = threadIdx.x;
    float4 x = make_float4(0.f, 0.f, 0.f, 0.f);
    if (tt < HDIM / 4) {
        float4 a = ((const float4*)(WE + (size_t)id * HDIM))[tt];
        float4 b = ((const float4*)(PE + (size_t)s * HDIM))[tt];
        x = make_float4(a.x + b.x, a.y + b.y, a.z + b.z, a.w + b.w);
    }
    float s1 = blk_sum256(x.x + x.y + x.z + x.w, sm);
    float s2 = blk_sum256(x.x*x.x + x.y*x.y + x.z*x.z + x.w*x.w, sm);
    float mean = s1 * (1.f / HDIM);
    float var  = s2 * (1.f / HDIM) - mean * mean;
    float inv  = rsqrtf(var + 1e-5f);
    if (tt < HDIM / 4) {
        float4 gg = ((const float4*)g)[tt];
        float4 bb = ((const float4*)bta)[tt];
        float4 o;
        o.x = (x.x - mean) * inv * gg.x + bb.x;
        o.y = (x.y - mean) * inv * gg.y + bb.y;
        o.z = (x.z - mean) * inv * gg.z + bb.z;
        o.w = (x.w - mean) * inv * gg.w + bb.w;
        ((float4*)(h + (size_t)tok * HDIM))[tt] = o;
        uint2 pk;
        pk.x = (u32)f2bf(o.x) | ((u32)f2bf(o.y) << 16);
        pk.y = (u32)f2bf(o.z) | ((u32)f2bf(o.w) << 16);
        ((uint2*)(hb + (size_t)tok * HDIM))[tt] = pk;
    }
}

// ---------------- residual add + LN (h fp32 in place, hb bf16 out) ----------------
// t2 optional (split-K partial); h += t (+ t2), then LN
__global__ __launch_bounds__(256) void k_addln(
    float* __restrict__ h, const float* __restrict__ t, const float* __restrict__ t2,
    const float* __restrict__ g, const float* __restrict__ bta, u16* __restrict__ hb)
{
    __shared__ float sm[4];
    int tok = blockIdx.x;
    int tt = threadIdx.x;
    float4 x = make_float4(0.f, 0.f, 0.f, 0.f);
    if (tt < HDIM / 4) {
        float4 a = ((const float4*)(h + (size_t)tok * HDIM))[tt];
        float4 b = ((const float4*)(t + (size_t)tok * HDIM))[tt];
        x = make_float4(a.x + b.x, a.y + b.y, a.z + b.z, a.w + b.w);
        if (t2) {
            float4 c = ((const float4*)(t2 + (size_t)tok * HDIM))[tt];
            x = make_float4(x.x + c.x, x.y + c.y, x.z + c.z, x.w + c.w);
        }
    }
    float s1 = blk_sum256(x.x + x.y + x.z + x.w, sm);
    float s2 = blk_sum256(x.x*x.x + x.y*x.y + x.z*x.z + x.w*x.w, sm);
    float mean = s1 * (1.f / HDIM);
    float var  = s2 * (1.f / HDIM) - mean * mean;
    float inv  = rsqrtf(var + 1e-5f);
    if (tt < HDIM / 4) {
        float4 gg = ((const float4*)g)[tt];
        float4 bb = ((const float4*)bta)[tt];
        float4 o;
        o.x = (x.x - mean) * inv * gg.x + bb.x;
        o.y = (x.y - mean) * inv * gg.y + bb.y;
        o.z = (x.z - mean) * inv * gg.z + bb.z;
        o.w = (x.w - mean) * inv * gg.w + bb.w;
        ((float4*)(h + (size_t)tok * HDIM))[tt] = o;
        uint2 pk;
        pk.x = (u32)f2bf(o.x) | ((u32)f2bf(o.y) << 16);
        pk.y = (u32)f2bf(o.z) | ((u32)f2bf(o.w) << 16);
        ((uint2*)(hb + (size_t)tok * HDIM))[tt] = pk;
    }
}

// ---------------- transpose + fp32->bf16: W[K][N] -> dst[N][K] ----------------
// grid (N/32, K/32, nlayers), 256 threads; ss/ds = per-layer element strides
__global__ __launch_bounds__(256) void k_cvtT(
    const float* __restrict__ W, u16* __restrict__ dst, int K, int N,
    size_t ss, size_t ds)
{
    __shared__ float t[32][33];
    W   += (size_t)blockIdx.z * ss;
    dst += (size_t)blockIdx.z * ds;
    int n0 = blockIdx.x * 32, k0 = blockIdx.y * 32;
    int c = threadIdx.x & 31, r8 = threadIdx.x >> 5;
#pragma unroll
    for (int p = 0; p < 4; p++) {
        int k = r8 + p * 8;
        t[k][c] = W[(size_t)(k0 + k) * N + n0 + c];
    }
    __syncthreads();
#pragma unroll
    for (int p = 0; p < 2; p++) {
        int idx = threadIdx.x + p * 256;       // 0..511 over 32 n-rows x 16 k-pairs
        int n = idx >> 4, kp = idx & 15;
        float a = t[kp*2][n], b = t[kp*2+1][n];
        u32 pk = (u32)f2bf(a) | ((u32)f2bf(b) << 16);
        u32* d = (u32*)(dst + (size_t)(n0 + n) * K + k0);
        d[kp] = pk;
    }
}

// ---------------- MFMA GEMM: C[M,N] = A[M,K](bf16) @ BT[N,K]^T(bf16) ----------------
// NS BK=32 K-subtiles staged per barrier pair (LDS [NS][BM][32]). NS=2 verified
// optimal (NS=3 regressed: occupancy). Blocks xcd_swz-remapped per z-slice.
// Split-K: gridDim.z slices; slice z covers K range [z*Klen, (z+1)*Klen), writes
// C + z*MTOK*N (MODE 0 only); bias added only in slice 0. Klen==K for no split.
// MODE 0: C fp32 [M,N] (+bias b0)
// MODE 1: QKV split -> bf16 planes [3][B,NH,S,DH], biases b0/b1/b2
// MODE 2: GELU -> bf16 [M,N]
template<int BM, int BN, int MODE, int NS>
__global__ __launch_bounds__(256) void k_gemm_mfma(
    const u16* __restrict__ A, const u16* __restrict__ BT,
    const float* __restrict__ b0, const float* __restrict__ b1, const float* __restrict__ b2,
    void* __restrict__ C, int K, int Klen, int N)
{
    __shared__ u16 As[NS * BM * 32];
    __shared__ u16 Bs[NS * BN * 32];
    const int tid = threadIdx.x, lane = tid & 63, w = tid >> 6;
    int flat = blockIdx.y * gridDim.x + blockIdx.x;
    flat = xcd_swz(flat, gridDim.x * gridDim.y);
    const int bm = (flat / gridDim.x) * BM, bn = (flat % gridDim.x) * BN;
    const int kbase = blockIdx.z * Klen;
    constexpr int MT = BM / 32, NT = BN / 32;      // mfma tiles per wave
    constexpr int AR = BM / 4, BR = BN / 4;        // staging rows per wave
    constexpr int AI = AR / 16, BI = BR / 16;      // lds-dma instrs per wave per subtile
    const int wm = (w & 1) * (BM / 2), wn = (w >> 1) * (BN / 2);

    f32x4 acc[MT][NT];
#pragma unroll
    for (int mi = 0; mi < MT; mi++)
#pragma unroll
        for (int ni = 0; ni < NT; ni++) acc[mi][ni] = (f32x4){0.f, 0.f, 0.f, 0.f};

    const u16* ag = A  + (size_t)(bm + w * AR + (lane >> 2)) * K + kbase + (lane & 3) * 8;
    const u16* bg = BT + (size_t)(bn + w * BR + (lane >> 2)) * K + kbase + (lane & 3) * 8;
    u16* al = As + w * AR * 32;
    u16* bl = Bs + w * BR * 32;
    const int fr = lane & 15, fq = (lane >> 4) * 8;

    for (int k0 = 0; k0 < Klen; k0 += 32 * NS) {
#pragma unroll
        for (int s = 0; s < NS; s++) {
#pragma unroll
            for (int i = 0; i < AI; i++)
                gload16(ag + (size_t)i * 16 * K + k0 + s * 32, al + s * BM * 32 + i * 512);
#pragma unroll
            for (int i = 0; i < BI; i++)
                gload16(bg + (size_t)i * 16 * K + k0 + s * 32, bl + s * BN * 32 + i * 512);
        }
        __syncthreads();
#pragma unroll
        for (int s = 0; s < NS; s++) {
            bf16x8 af[MT], bf[NT];
#pragma unroll
            for (int mi = 0; mi < MT; mi++)
                af[mi] = *(const bf16x8*)(As + s * BM * 32 + (wm + mi * 16 + fr) * 32 + fq);
#pragma unroll
            for (int ni = 0; ni < NT; ni++)
                bf[ni] = *(const bf16x8*)(Bs + s * BN * 32 + (wn + ni * 16 + fr) * 32 + fq);
#pragma unroll
            for (int mi = 0; mi < MT; mi++)
#pragma unroll
                for (int ni = 0; ni < NT; ni++)
                    acc[mi][ni] = __builtin_amdgcn_mfma_f32_16x16x32_bf16(af[mi], bf[ni], acc[mi][ni], 0, 0, 0);
        }
        __syncthreads();
    }

    float* Cz = (MODE == 0) ? ((float*)C + (size_t)blockIdx.z * MTOK * N) : (float*)C;
#pragma unroll
    for (int mi = 0; mi < MT; mi++) {
        int m_base = bm + wm + mi * 16 + (lane >> 4) * 4;
#pragma unroll
        for (int ni = 0; ni < NT; ni++) {
            int n_g = bn + wn + ni * 16 + (lane & 15);
            const float* bp = b0; int nn = n_g; int which = 0;
            if (MODE == 1) {
                if (n_g >= 1536)      { bp = b2; nn = n_g - 1536; which = 2; }
                else if (n_g >= 768)  { bp = b1; nn = n_g - 768;  which = 1; }
            }
            float bias = (MODE == 0 && blockIdx.z != 0) ? 0.f : bp[nn];
#pragma unroll
            for (int r = 0; r < 4; r++) {
                int m_g = m_base + r;
                float val = acc[mi][ni][r] + bias;
                if (MODE == 0) {
                    Cz[(size_t)m_g * N + n_g] = val;
                } else if (MODE == 1) {
                    int bb = m_g >> 10, ss = m_g & 1023;
                    int hh = nn >> 6, dd = nn & 63;
                    ((u16*)C)[(size_t)which * PLANE + (((size_t)bb * NHEAD + hh) * SEQ + ss) * DHEAD + dd] = f2bf(val);
                } else {
                    val = 0.5f * val * (1.f + erff(val * 0.70710678118f));
                    ((u16*)C)[(size_t)m_g * N + n_g] = f2bf(val);
                }
            }
        }
    }
}

// ---------------- MFMA banded local attention ----------------
// One block per (b, h, 64-row q tile). 4 waves; wave w owns q rows [w*16, w*16+16).
// Keys iterated in 9 chunks of 64 covering span [q0-256, q0+319].
// QK^T and PV both via mfma_f32_16x16x32_bf16; online softmax held in registers
// (each lane owns 4 q rows; row-reduce = shfl_xor butterfly over the 16 key lanes).
// LDS rows padded to 72 u16 (144 B). Blocks xcd_swz-remapped so same-head q-tiles
// (overlapping K/V windows) co-locate on one XCD's L2.
#define PADW 72
__global__ __launch_bounds__(256) void k_attn_mfma(
    const u16* __restrict__ qkv, const int* __restrict__ mask, u16* __restrict__ abuf)
{
    __shared__ u16 Qs[64 * PADW];
    __shared__ u16 Ks[64 * PADW];
    __shared__ u16 Vt[64 * PADW];   // transposed: [dh][key]
    __shared__ u16 Ps[64 * PADW];   // probs bf16: [q][key]
    __shared__ int ms[64];
    const int tid = threadIdx.x, lane = tid & 63, w = tid >> 6;
    int blk = xcd_swz(blockIdx.x, gridDim.x);
    int qt = blk & 15;
    int hh = (blk >> 4) % NHEAD;
    int b  = blk / (16 * NHEAD);
    int q0 = qt * 64;

    const u16* qp = qkv + ((size_t)b * NHEAD + hh) * SEQ * DHEAD;
    const u16* kp = qp + PLANE;
    const u16* vp = qp + 2 * PLANE;

    // stage Q tile [64][64] once
#pragma unroll
    for (int it = 0; it < 2; it++) {
        int idx = tid + it * 256;            // 512 segs = 64 rows x 8 col-segs
        int r = idx >> 3, c8 = (idx & 7) * 8;
        uint4 u = *(const uint4*)(qp + (size_t)(q0 + r) * DHEAD + c8);
        *(uint4*)(Qs + r * PADW + c8) = u;
    }

    const int fr = lane & 15, g4 = (lane >> 4) * 4, fq = (lane >> 4) * 8;
    const int wq = w * 16;
    const int qpos = q0 + wq + g4;           // +r gives this lane's q rows

    f32x4 o[4];                               // out acc: [dh tile][q row r]
#pragma unroll
    for (int d = 0; d < 4; d++) o[d] = (f32x4){0.f, 0.f, 0.f, 0.f};
    float mr[4], ll[4];
#pragma unroll
    for (int r = 0; r < 4; r++) { mr[r] = -1e9f; ll[r] = 0.f; }

    __syncthreads();
    bf16x8 aq[2];                             // Q A-frags, persist across chunks
#pragma unroll
    for (int ks = 0; ks < 2; ks++)
        aq[ks] = *(const bf16x8*)(Qs + (wq + fr) * PADW + ks * 32 + fq);

    for (int ch = 0; ch < 9; ch++) {
        int kbase = q0 - 256 + ch * 64;
        __syncthreads();                      // prev chunk's PV reads done
        // stage K rows [64][64]
#pragma unroll
        for (int it = 0; it < 2; it++) {
            int idx = tid + it * 256;
            int r = idx >> 3, c8 = (idx & 7) * 8;
            int kq = kbase + r;
            uint4 u = (kq >= 0 && kq < SEQ)
                ? *(const uint4*)(kp + (size_t)kq * DHEAD + c8)
                : make_uint4(0u, 0u, 0u, 0u);
            *(uint4*)(Ks + r * PADW + c8) = u;
        }
        // stage V transposed: thread handles key r = tid>>2, dh seg (tid&3)*16
        {
            int r = tid >> 2, sg = (tid & 3) * 16;
            int kq = kbase + r;
            uint4 u0 = make_uint4(0u,0u,0u,0u), u1 = u0;
            if (kq >= 0 && kq < SEQ) {
                const uint4* vr = (const uint4*)(vp + (size_t)kq * DHEAD + sg);
                u0 = vr[0]; u1 = vr[1];
            }
            u32 ww[8] = {u0.x, u0.y, u0.z, u0.w, u1.x, u1.y, u1.z, u1.w};
#pragma unroll
            for (int j = 0; j < 8; j++) {
                Vt[(sg + 2*j    ) * PADW + r] = (u16)(ww[j] & 0xffffu);
                Vt[(sg + 2*j + 1) * PADW + r] = (u16)(ww[j] >> 16);
            }
        }
        if (tid < 64) {
            int kq = kbase + tid;
            ms[tid] = (kq >= 0 && kq < SEQ) ? mask[b * SEQ + kq] : 0;
        }
        __syncthreads();

        // QK^T: s[nt][r] = score[q = wq+g4+r][key = nt*16+fr]
        f32x4 s[4];
#pragma unroll
        for (int nt = 0; nt < 4; nt++) s[nt] = (f32x4){0.f, 0.f, 0.f, 0.f};
#pragma unroll
        for (int nt = 0; nt < 4; nt++)
#pragma unroll
            for (int ks = 0; ks < 2; ks++) {
                bf16x8 bk = *(const bf16x8*)(Ks + (nt*16 + fr) * PADW + ks*32 + fq);
                s[nt] = __builtin_amdgcn_mfma_f32_16x16x32_bf16(aq[ks], bk, s[nt], 0, 0, 0);
            }

        // scale + band/mask, per-lane chunk max
        float mloc[4];
#pragma unroll
        for (int r = 0; r < 4; r++) mloc[r] = -1e9f;
#pragma unroll
        for (int nt = 0; nt < 4; nt++) {
            int kpos = kbase + nt*16 + fr;
            int msv = ms[nt*16 + fr];
#pragma unroll
            for (int r = 0; r < 4; r++) {
                int dq = kpos - (qpos + r);
                bool ok = (dq >= -WINSZ) && (dq <= WINSZ) && (msv != 0);
                float sv = ok ? s[nt][r] * 0.125f : -1e9f;
                s[nt][r] = sv;
                mloc[r] = fmaxf(mloc[r], sv);
            }
        }
        // butterfly max over the 16 key lanes
#pragma unroll
        for (int mk = 1; mk < 16; mk <<= 1)
#pragma unroll
            for (int r = 0; r < 4; r++)
                mloc[r] = fmaxf(mloc[r], __shfl_xor(mloc[r], mk, 64));

        float sc4[4], psum[4];
#pragma unroll
        for (int r = 0; r < 4; r++) {
            float mn = fmaxf(mr[r], mloc[r]);
            sc4[r] = __expf(mr[r] - mn);
            mr[r] = mn;
            psum[r] = 0.f;
        }
        // p = exp(s - m), write bf16 P to LDS (rows owned by this wave only)
#pragma unroll
        for (int nt = 0; nt < 4; nt++)
#pragma unroll
            for (int r = 0; r < 4; r++) {
                float p = (s[nt][r] > -1e8f) ? __expf(s[nt][r] - mr[r]) : 0.f;
                psum[r] += p;
                Ps[(wq + g4 + r) * PADW + nt*16 + fr] = f2bf(p);
            }
        // butterfly sum over key lanes
#pragma unroll
        for (int mk = 1; mk < 16; mk <<= 1)
#pragma unroll
            for (int r = 0; r < 4; r++)
                psum[r] += __shfl_xor(psum[r], mk, 64);

        f32x4 scv = (f32x4){sc4[0], sc4[1], sc4[2], sc4[3]};
#pragma unroll
        for (int r = 0; r < 4; r++) ll[r] = ll[r] * sc4[r] + psum[r];
#pragma unroll
        for (int d = 0; d < 4; d++) o[d] *= scv;

        // PV: o[d] += P[q,keys] @ Vt[dh,keys]^T  (same-wave LDS write->read, in-order)
#pragma unroll
        for (int ks = 0; ks < 2; ks++) {
            bf16x8 ap = *(const bf16x8*)(Ps + (wq + fr) * PADW + ks*32 + fq);
#pragma unroll
            for (int d = 0; d < 4; d++) {
                bf16x8 bv8 = *(const bf16x8*)(Vt + (d*16 + fr) * PADW + ks*32 + fq);
                o[d] = __builtin_amdgcn_mfma_f32_16x16x32_bf16(ap, bv8, o[d], 0, 0, 0);
            }
        }
    }

    // epilogue: normalize and store bf16 to abuf[B,S,H]
#pragma unroll
    for (int r = 0; r < 4; r++) {
        float inv = 1.f / ll[r];
        u16* orow = abuf + ((size_t)(b * SEQ + q0 + wq + g4 + r)) * HDIM + hh * DHEAD;
#pragma unroll
        for (int d = 0; d < 4; d++)
            orow[d*16 + fr] = f2bf(o[d][r] * inv);
    }
}

// ---------------- attention-pool head (parallelized) ----------------
// Phase A: sc[tok] = h[tok]·aw — one wave per token, grid MTOK/4 x 256
__global__ __launch_bounds__(256) void k_pool_score(
    const float* __restrict__ h, const float* __restrict__ aw, float* __restrict__ sc)
{
    int tok = blockIdx.x * 4 + (threadIdx.x >> 6);
    int lane = threadIdx.x & 63;
    const float4* hr = (const float4*)(h + (size_t)tok * HDIM);
    const float4* ar = (const float4*)aw;
    float acc = 0.f;
#pragma unroll
    for (int i = 0; i < 3; i++) {
        int c = lane + i * 64;               // 192 float4 per row
        float4 x = hr[c], a = ar[c];
        acc += x.x*a.x + x.y*a.y + x.z*a.z + x.w*a.w;
    }
    acc = wave_sum(acc);
    if (lane == 0) sc[tok] = acc;
}

// Phase B: softmax over s per batch — grid B x 1024; sc in-place -> probs
__global__ __launch_bounds__(1024) void k_pool_softmax(float* __restrict__ sc)
{
    __shared__ float red[16];
    int b = blockIdx.x;
    float v = sc[b * SEQ + threadIdx.x];
    float mx = blk_max1024(v, red);
    float e = __expf(v - mx);
    float tot = blk_sum1024(e, red);
    sc[b * SEQ + threadIdx.x] = e / tot;
}

// Phase C: partial weighted sums over 64-row s-slices — grid (B,16) x 256
// partial[b][j][d] = sum_{s in slice j} h[b][s][d] * ps[b][s]
__global__ __launch_bounds__(256) void k_pool_reduce(
    const float* __restrict__ h, const float* __restrict__ ps, float* __restrict__ partial)
{
    int b = blockIdx.x, j = blockIdx.y;
    int tid = threadIdx.x;
    const float* hb = h + ((size_t)b * SEQ + j * 64) * HDIM;
    const float* pp = ps + b * SEQ + j * 64;
    float a0 = 0.f, a1 = 0.f, a2 = 0.f;
    for (int s = 0; s < 64; s++) {
        float p = pp[s];
        const float* row = hb + (size_t)s * HDIM;
        a0 = fmaf(row[tid],       p, a0);
        a1 = fmaf(row[tid + 256], p, a1);
        a2 = fmaf(row[tid + 512], p, a2);
    }
    float* outp = partial + ((size_t)b * 16 + j) * HDIM;
    outp[tid] = a0; outp[tid + 256] = a1; outp[tid + 512] = a2;
}

// Phase D: reduce 16 partials, dot with Wc — grid B x 256
__global__ __launch_bounds__(256) void k_pool_final(
    const float* __restrict__ partial, const float* __restrict__ Wc,
    const float* __restrict__ bc, float* __restrict__ out)
{
    __shared__ float sm[4];
    int b = blockIdx.x, tid = threadIdx.x;
    float acc = 0.f;
#pragma unroll
    for (int dd = 0; dd < 3; dd++) {
        int d = tid + dd * 256;
        float pd = 0.f;
#pragma unroll
        for (int j = 0; j < 16; j++)
            pd += partial[((size_t)b * 16 + j) * HDIM + d];
        acc = fmaf(pd, Wc[d], acc);
    }
    float total = blk_sum256(acc, sm);
    if (tid == 0) out[b] = total + bc[0];
}

// ---------------- launcher ----------------
extern "C" void kernel_launch(void* const* d_in, const int* in_sizes, int n_in,
                              void* d_out, int out_size, void* d_ws, size_t ws_size,
                              hipStream_t stream)
{
    const float* WE    = (const float*)d_in[0];
    const float* PE    = (const float*)d_in[1];
    const float* Eg    = (const float*)d_in[2];
    const float* Eb    = (const float*)d_in[3];
    const float* Wq    = (const float*)d_in[4];
    const float* bq    = (const float*)d_in[5];
    const float* Wk    = (const float*)d_in[6];
    const float* bk    = (const float*)d_in[7];
    const float* Wv    = (const float*)d_in[8];
    const float* bv    = (const float*)d_in[9];
    const float* Wo    = (const float*)d_in[10];
    const float* bo    = (const float*)d_in[11];
    const float* g1    = (const float*)d_in[12];
    const float* beta1 = (const float*)d_in[13];
    const float* W1    = (const float*)d_in[14];
    const float* b1    = (const float*)d_in[15];
    const float* W2    = (const float*)d_in[16];
    const float* b2    = (const float*)d_in[17];
    const float* g2    = (const float*)d_in[18];
    const float* beta2 = (const float*)d_in[19];
    const float* aw    = (const float*)d_in[20];
    const float* Wc    = (const float*)d_in[21];
    const float* bc    = (const float*)d_in[22];
    const int* ids     = (const int*)d_in[23];
    const int* msk     = (const int*)d_in[24];

    char* base = (char*)d_ws;
    float* h     = (float*)base;                              base += (size_t)MTOK * HDIM * 4;   // 12.6MB
    float* tbuf  = (float*)base;                              base += (size_t)MTOK * HDIM * 4;   // 12.6MB
    float* tbuf2 = (float*)base;                              base += (size_t)MTOK * HDIM * 4;   // 12.6MB (split-K partial)
    u16*   hb    = (u16*)base;                                base += (size_t)MTOK * HDIM * 2;   // 6.3MB
    u16*   X     = (u16*)base;                                base += (size_t)MTOK * FFDIM * 2;  // 25.2MB
    u16*   qkv   = X;                                         // 3 planes of PLANE
    u16*   abuf  = X + 3 * PLANE;                             // [B,S,H] bf16
    u16*   mid   = X;                                         // FF1 out aliases qkv/abuf (dead)

    // weight buffers: if workspace allows, convert ALL layers once up front
    const size_t sQKV = (size_t)2304 * HDIM;   // per-layer elems
    const size_t sWO  = (size_t)HDIM * HDIM;
    const size_t sW1  = (size_t)FFDIM * HDIM;
    const size_t sW2  = (size_t)HDIM * FFDIM;
    size_t fixed = (size_t)(base - (char*)d_ws);
    size_t all_bytes = fixed + (size_t)LAYERS * (sQKV + sWO + sW1 + sW2) * 2;
    bool wsall = ws_size >= all_bytes;
    int NL = wsall ? LAYERS : 1;
    u16* wqkvT = (u16*)base;
    u16* woT   = wqkvT + sQKV * NL;
    u16* w1T   = woT   + sWO  * NL;
    u16* w2T   = w1T   + sW1  * NL;

    k_embed_ln<<<MTOK, 256, 0, stream>>>(WE, PE, Eg, Eb, ids, h, hb);

    if (wsall) {
        k_cvtT<<<dim3(24, 24, LAYERS), 256, 0, stream>>>(Wq, wqkvT,                     HDIM, HDIM, (size_t)HDIM*HDIM, sQKV);
        k_cvtT<<<dim3(24, 24, LAYERS), 256, 0, stream>>>(Wk, wqkvT + (size_t)HDIM*HDIM, HDIM, HDIM, (size_t)HDIM*HDIM, sQKV);
        k_cvtT<<<dim3(24, 24, LAYERS), 256, 0, stream>>>(Wv, wqkvT + (size_t)2*HDIM*HDIM, HDIM, HDIM, (size_t)HDIM*HDIM, sQKV);
        k_cvtT<<<dim3(24, 24, LAYERS), 256, 0, stream>>>(Wo, woT, HDIM, HDIM, (size_t)HDIM*HDIM, sWO);
        k_cvtT<<<dim3(96, 24, LAYERS), 256, 0, stream>>>(W1, w1T, HDIM, FFDIM, (size_t)HDIM*FFDIM, sW1);
        k_cvtT<<<dim3(24, 96, LAYERS), 256, 0, stream>>>(W2, w2T, FFDIM, HDIM, (size_t)FFDIM*HDIM, sW2);
    }

    for (int l = 0; l < LAYERS; l++) {
        u16* wqkvT_l = wqkvT + (wsall ? (size_t)l * sQKV : 0);
        u16* woT_l   = woT   + (wsall ? (size_t)l * sWO  : 0);
        u16* w1T_l   = w1T   + (wsall ? (size_t)l * sW1  : 0);
        u16* w2T_l   = w2T   + (wsall ? (size_t)l * sW2  : 0);

        if (!wsall) {
            const float* Wql = Wq + (size_t)l * HDIM * HDIM;
            const float* Wkl = Wk + (size_t)l * HDIM * HDIM;
            const float* Wvl = Wv + (size_t)l * HDIM * HDIM;
            const float* Wol = Wo + (size_t)l * HDIM * HDIM;
            const float* W1l = W1 + (size_t)l * HDIM * FFDIM;
            const float* W2l = W2 + (size_t)l * FFDIM * HDIM;
            k_cvtT<<<dim3(24, 24), 256, 0, stream>>>(Wql, wqkvT_l,                      HDIM, HDIM, 0, 0);
            k_cvtT<<<dim3(24, 24), 256, 0, stream>>>(Wkl, wqkvT_l + (size_t)HDIM*HDIM,  HDIM, HDIM, 0, 0);
            k_cvtT<<<dim3(24, 24), 256, 0, stream>>>(Wvl, wqkvT_l + (size_t)2*HDIM*HDIM,HDIM, HDIM, 0, 0);
            k_cvtT<<<dim3(24, 24), 256, 0, stream>>>(Wol, woT_l, HDIM, HDIM, 0, 0);
            k_cvtT<<<dim3(96, 24), 256, 0, stream>>>(W1l, w1T_l, HDIM, FFDIM, 0, 0);
            k_cvtT<<<dim3(24, 96), 256, 0, stream>>>(W2l, w2T_l, FFDIM, HDIM, 0, 0);
        }

        // QKV fused: [4096,768] @ [768,2304]
        k_gemm_mfma<128, 128, 1, 2><<<dim3(2304/128, MTOK/128), 256, 0, stream>>>(
            hb, wqkvT_l, bq + l*HDIM, bk + l*HDIM, bv + l*HDIM, qkv, HDIM, HDIM, 2304);
        // banded attention (MFMA)
        k_attn_mfma<<<BATCH * NHEAD * (SEQ/64), 256, 0, stream>>>(qkv, msk, abuf);
        // attn out proj: [4096,768] @ [768,768] -> fp32
        k_gemm_mfma<128, 64, 0, 2><<<dim3(HDIM/64, MTOK/128), 256, 0, stream>>>(
            abuf, woT_l, bo + l*HDIM, nullptr, nullptr, tbuf, HDIM, HDIM, HDIM);
        k_addln<<<MTOK, 256, 0, stream>>>(h, tbuf, nullptr, g1 + l*HDIM, beta1 + l*HDIM, hb);
        // FF1 + gelu: [4096,768] @ [768,3072] -> bf16
        k_gemm_mfma<128, 128, 2, 2><<<dim3(FFDIM/128, MTOK/128), 256, 0, stream>>>(
            hb, w1T_l, b1 + l*FFDIM, nullptr, nullptr, mid, HDIM, HDIM, FFDIM);
        // FF2: [4096,3072] @ [3072,768] -> fp32, split-K=2 (z-slices -> tbuf/tbuf2)
        k_gemm_mfma<128, 64, 0, 2><<<dim3(HDIM/64, MTOK/128, 2), 256, 0, stream>>>(
            mid, w2T_l, b2 + l*HDIM, nullptr, nullptr, tbuf, FFDIM, FFDIM/2, HDIM);
        k_addln<<<MTOK, 256, 0, stream>>>(h, tbuf, tbuf2, g2 + l*HDIM, beta2 + l*HDIM, hb);
    }

    // pool scratch lives in tbuf (dead after the layer loop)
    float* ps      = tbuf;                 // [B][SEQ] probs
    float* partial = tbuf + BATCH * SEQ;   // [B][16][HDIM] partial sums
    k_pool_score  <<<MTOK / 4, 256, 0, stream>>>(h, aw, ps);
    k_pool_softmax<<<BATCH, 1024, 0, stream>>>(ps);
    k_pool_reduce <<<dim3(BATCH, 16), 256, 0, stream>>>(h, ps, partial);
    k_pool_final  <<<BATCH, 256, 0, stream>>>(partial, Wc, bc, (float*)d_out);
}